// Round 9
// baseline (326.331 us; speedup 1.0000x reference)
//
#include <hip/hip_runtime.h>

// GCNBlock: out0 = relu( (D^-1/2 (A+I) D^-1/2) (x W) + b ) + x   [N,128] f32
//           out1 = edge_index echoed (as float values) appended in d_out
// Identity: Agg(xW) = Agg(x) W.
// Round 9: 10 -> 6 launches. agg+gemm fused via 16KB LDS tile (kills aggh
// HBM round-trip); inline is64 detection (kills k_sniff); local colsum scans
// (kills k_scanH2); cvt_W folded into kA1 grid; nontemporal scatter stores.

#define DD 128
#define EPB 2048      // edges per A-block (8 iters x 256 threads)
#define BSH 9         // bucket shift: 512 nodes per bucket
typedef __attribute__((ext_vector_type(8))) short bf16x8;
typedef __attribute__((ext_vector_type(4))) float f32x4;

__device__ __forceinline__ ushort f2bf(float f) {
    unsigned u = __float_as_uint(f);
    unsigned r = (u + 0x7fffu + ((u >> 16) & 1u)) >> 16;  // RNE
    return (ushort)r;
}
__device__ __forceinline__ float bflo(unsigned u) { return __uint_as_float(u << 16); }
__device__ __forceinline__ float bfhi(unsigned u) { return __uint_as_float(u & 0xffff0000u); }

__device__ __forceinline__ int ld_src(const int* p, int e, int E, int is64) {
    return is64 ? p[2 * e] : p[e];
}
__device__ __forceinline__ int ld_dst(const int* p, int e, int E, int is64) {
    return is64 ? p[2 * (E + e)] : p[E + e];
}

// inline dtype sniff: int64 edge data has all-zero high words.
// Every wave reads the SAME first 128 ints (L2-hot) -> identical result.
__device__ __forceinline__ int detect64(const int* __restrict__ p, int E) {
    int lane = threadIdx.x & 63;
    int idx = 2 * lane + 1;
    if (idx >= 2 * E) idx = 2 * E - 1;
    unsigned long long m = __ballot(p[idx] != 0);
    return m == 0ull ? 1 : 0;
}

// ---------- A1: bucket histogram + fused echo (+ tail blocks convert W) ----------
__global__ __launch_bounds__(256) void kA1(const int* __restrict__ ei, int E, int NB, int nA,
                                           float* __restrict__ outTail, int* __restrict__ H,
                                           const float* __restrict__ W, ushort* __restrict__ Wt) {
    int t = threadIdx.x, a = blockIdx.x;
    if (a >= nA) {  // W-conversion tail blocks
        int i = (a - nA) * 256 + t;
        if (i < DD * DD) {
            int c = i >> 7, k = i & 127;
            Wt[i] = f2bf(W[k * DD + c]);
        }
        return;
    }
    __shared__ int hist[256];
    int is64 = detect64(ei, E);
    if (t < NB) hist[t] = 0;
    __syncthreads();
    int base = a * EPB;
    #pragma unroll
    for (int it = 0; it < EPB / 256; ++it) {
        int e = base + it * 256 + t;
        if (e < E) {
            int s = ld_src(ei, e, E, is64);
            int d = ld_dst(ei, e, E, is64);
            __builtin_nontemporal_store((float)s, &outTail[e]);
            __builtin_nontemporal_store((float)d, &outTail[E + e]);
            atomicAdd(&hist[d >> BSH], 1);
        }
    }
    __syncthreads();
    if (t < NB) H[a * NB + t] = hist[t];
}

// ---------- scanH1: per-column exclusive scan of H (NB blocks, nA<=1024) ----------
__global__ __launch_bounds__(256) void k_scanH1(int* __restrict__ H, int nA, int NB,
                                                int* __restrict__ colsum) {
    __shared__ int s[256];
    int b = blockIdx.x, t = threadIdx.x;
    int K = (nA + 255) / 256;
    int base = t * K;
    int local = 0;
    for (int j = 0; j < K; ++j) {
        int a = base + j;
        if (a < nA) local += H[a * NB + b];
    }
    s[t] = local;
    __syncthreads();
    #pragma unroll
    for (int off = 1; off < 256; off <<= 1) {
        int u = (t >= off) ? s[t - off] : 0;
        __syncthreads();
        s[t] += u;
        __syncthreads();
    }
    int run = s[t] - local;  // exclusive prefix of this thread's chunk
    for (int j = 0; j < K; ++j) {
        int a = base + j;
        if (a < nA) { int v = H[a * NB + b]; H[a * NB + b] = run; run += v; }
    }
    if (t == 255) colsum[b] = s[255];
}

// ---------- A2: scatter packed records; bucketstart derived locally from colsum ----
// record = src | (dst&511)<<17   (needs N <= 131072)
__global__ __launch_bounds__(256) void kA2(const int* __restrict__ ei, int E, int NB,
                                           const int* __restrict__ H,
                                           const int* __restrict__ colsum,
                                           unsigned* __restrict__ brec) {
    __shared__ int bs[256];
    __shared__ int cur[256];
    int t = threadIdx.x, a = blockIdx.x;
    int is64 = detect64(ei, E);
    int v = (t < NB) ? colsum[t] : 0;
    bs[t] = v;
    __syncthreads();
    #pragma unroll
    for (int off = 1; off < 256; off <<= 1) {
        int u = (t >= off) ? bs[t - off] : 0;
        __syncthreads();
        bs[t] += u;
        __syncthreads();
    }
    if (t < NB) cur[t] = H[a * NB + t] + bs[t] - v;  // exclusive bucketstart + block offset
    __syncthreads();
    int base = a * EPB;
    #pragma unroll
    for (int it = 0; it < EPB / 256; ++it) {
        int e = base + it * 256 + t;
        if (e < E) {
            int s = ld_src(ei, e, E, is64);
            int d = ld_dst(ei, e, E, is64);
            int pos = atomicAdd(&cur[d >> BSH], 1);  // LDS atomic
            __builtin_nontemporal_store((unsigned)s | ((unsigned)(d & 511) << 17), &brec[pos]);
        }
    }
}

// ---------- B: per-bucket CSR finalize: recs + rowstart + invs ----------
__global__ __launch_bounds__(256) void kB(const unsigned* __restrict__ brec,
                                          const int* __restrict__ colsum, int NB, int N,
                                          int E, unsigned* __restrict__ recs,
                                          int* __restrict__ rowstart, float* __restrict__ invs) {
    __shared__ int bs[256];
    __shared__ int hist[512];
    __shared__ int scan[513];
    __shared__ int cur[512];
    int b = blockIdx.x, t = threadIdx.x;
    int v = (t < NB) ? colsum[t] : 0;
    bs[t] = v;
    __syncthreads();
    #pragma unroll
    for (int off = 1; off < 256; off <<= 1) {
        int u = (t >= off) ? bs[t - off] : 0;
        __syncthreads();
        bs[t] += u;
        __syncthreads();
    }
    if (t < NB) bs[t] -= v;  // exclusive
    hist[t] = 0; hist[t + 256] = 0;
    __syncthreads();
    int lo = bs[b], hi = lo + colsum[b];
    for (int i = lo + t; i < hi; i += 256) atomicAdd(&hist[brec[i] >> 17], 1);
    __syncthreads();
    if (t == 0) {
        int acc = 0;
        for (int j = 0; j < 512; ++j) { scan[j] = acc; acc += hist[j]; }
        scan[512] = acc;
    }
    __syncthreads();
    int nodeBase = b << BSH;
    #pragma unroll
    for (int j = t; j < 512; j += 256) {
        int node = nodeBase + j;
        if (node < N) {
            rowstart[node] = lo + scan[j];
            invs[node] = rsqrtf((float)(1 + hist[j]));  // deg includes self-loop
        }
        cur[j] = lo + scan[j];
    }
    if (b == NB - 1 && t == 0) rowstart[N] = E;
    __syncthreads();
    for (int i = lo + t; i < hi; i += 256) {
        unsigned r = brec[i];
        int pos = atomicAdd(&cur[r >> 17], 1);  // LDS atomic
        __builtin_nontemporal_store(r & 0x1FFFFu, &recs[pos]);
    }
}

// ---------- convert x -> bf16 pre-scaled by invs: xs[i] = bf16(invs[node]*x[i]) ----------
__global__ void k_cvt_xs(const float2* __restrict__ x2, const float* __restrict__ invs,
                         unsigned* __restrict__ xs, int n2) {
    int i = blockIdx.x * blockDim.x + threadIdx.x;
    if (i < n2) {
        float w = invs[i >> 6];
        float2 v = x2[i];
        xs[i] = (unsigned)f2bf(w * v.x) | ((unsigned)f2bf(w * v.y) << 16);
    }
}

// ---------- fused aggregation + MFMA GEMM + bias + relu + residual ----------
// Phase 1: each wave gathers 16 nodes' pre-scaled bf16 rows into a 16KB LDS tile.
// Phase 2: swapped-operand MFMA (D = Wt_frag x agg_frag from LDS); each lane's
//          f32x4 acc = float4 of 4 consecutive out cols of one node row.
__global__ __launch_bounds__(256) void k_agg_gemm(const unsigned* __restrict__ xs,
                                                  const int* __restrict__ rowstart,
                                                  const float* __restrict__ invs,
                                                  const unsigned* __restrict__ recs,
                                                  const ushort* __restrict__ Wt,
                                                  const float* __restrict__ bb,
                                                  const float* __restrict__ x,
                                                  float* __restrict__ out, int N) {
    __shared__ unsigned sA[64 * 64];  // [row][uint col] = [64][256B] linear
    int wave = threadIdx.x >> 6, lane = threadIdx.x & 63;
    int rowBase = blockIdx.x * 64;

    // ---- gather phase ----
    for (int i = 0; i < 16; ++i) {
        int r = wave * 16 + i;
        int node = rowBase + r;
        if (node < N) {
            float wn = invs[node];
            unsigned us = xs[(size_t)node * 64 + lane];  // self: invs^2 * x after scale
            float accx = bflo(us), accy = bfhi(us);
            int e = rowstart[node], e1 = rowstart[node + 1];
            for (; e + 16 <= e1; e += 16) {
                unsigned sv[16], vv[16];
                #pragma unroll
                for (int j = 0; j < 16; ++j) sv[j] = recs[e + j];
                #pragma unroll
                for (int j = 0; j < 16; ++j) vv[j] = xs[(size_t)sv[j] * 64 + lane];
                #pragma unroll
                for (int j = 0; j < 16; ++j) { accx += bflo(vv[j]); accy += bfhi(vv[j]); }
            }
            if (e + 8 <= e1) {
                unsigned sv[8], vv[8];
                #pragma unroll
                for (int j = 0; j < 8; ++j) sv[j] = recs[e + j];
                #pragma unroll
                for (int j = 0; j < 8; ++j) vv[j] = xs[(size_t)sv[j] * 64 + lane];
                #pragma unroll
                for (int j = 0; j < 8; ++j) { accx += bflo(vv[j]); accy += bfhi(vv[j]); }
                e += 8;
            }
            for (; e < e1; ++e) {
                unsigned v0 = xs[(size_t)recs[e] * 64 + lane];
                accx += bflo(v0); accy += bfhi(v0);
            }
            float ox = accx * wn, oy = accy * wn;
            sA[r * 64 + lane] = (unsigned)f2bf(ox) | ((unsigned)f2bf(oy) << 16);
        } else {
            sA[r * 64 + lane] = 0;
        }
    }
    __syncthreads();

    // ---- gemm phase ----
    int rfrag = lane & 15, kgrp = lane >> 4;
    f32x4 zero = {0.f, 0.f, 0.f, 0.f};
    f32x4 acc[8];
    #pragma unroll
    for (int n = 0; n < 8; ++n) acc[n] = zero;

    const ushort* sSh = (const ushort*)sA + (wave * 16 + rfrag) * DD + kgrp * 8;  // B frag (nodes, LDS)
    const ushort* wbase = Wt + rfrag * DD + kgrp * 8;                             // A frag (W cols)

    #pragma unroll
    for (int ks = 0; ks < 4; ++ks) {
        bf16x8 bnode = *(const bf16x8*)(sSh + ks * 32);
        #pragma unroll
        for (int n = 0; n < 8; ++n) {
            bf16x8 aw = *(const bf16x8*)(wbase + n * 16 * DD + ks * 32);
            acc[n] = __builtin_amdgcn_mfma_f32_16x16x32_bf16(aw, bnode, acc[n], 0, 0, 0);
        }
    }

    int node = rowBase + wave * 16 + rfrag;
    if (node < N) {
        int csub = kgrp * 4;
        #pragma unroll
        for (int n = 0; n < 8; ++n) {
            int c0 = n * 16 + csub;
            float4 bv = *(const float4*)&bb[c0];
            float4 xv = *(const float4*)&x[(size_t)node * DD + c0];
            float4 o;
            o.x = fmaxf(acc[n][0] + bv.x, 0.f) + xv.x;
            o.y = fmaxf(acc[n][1] + bv.y, 0.f) + xv.y;
            o.z = fmaxf(acc[n][2] + bv.z, 0.f) + xv.z;
            o.w = fmaxf(acc[n][3] + bv.w, 0.f) + xv.w;
            *(float4*)&out[(size_t)node * DD + c0] = o;
        }
    }
}

// =================== fallback path (shape/ws outside new-path limits) ===================
__global__ void k_sniff(const int* __restrict__ p, int n_check, int* __restrict__ flag) {
    __shared__ int any_nonzero;
    if (threadIdx.x == 0) any_nonzero = 0;
    __syncthreads();
    int j = threadIdx.x;
    if (j < n_check && p[2 * j + 1] != 0) any_nonzero = 1;
    __syncthreads();
    if (threadIdx.x == 0) *flag = any_nonzero ? 0 : 1;
}

__global__ void k_count_echo(const int* __restrict__ ei, int E, int* __restrict__ cnt,
                             float* __restrict__ outTail, unsigned* __restrict__ rank,
                             const int* __restrict__ flagp) {
    int is64 = *flagp;
    int e = blockIdx.x * blockDim.x + threadIdx.x;
    if (e < E) {
        int s = ld_src(ei, e, E, is64);
        int d = ld_dst(ei, e, E, is64);
        outTail[e] = (float)s;
        outTail[E + e] = (float)d;
        rank[e] = (unsigned)atomicAdd(&cnt[d], 1);
    }
}

__global__ void k_scan1(const int* __restrict__ cnt, int N, int* __restrict__ rowstart,
                        int* __restrict__ bsum) {
    __shared__ int s[1024];
    int tid = threadIdx.x;
    int i = blockIdx.x * 1024 + tid;
    int v = (i < N) ? cnt[i] : 0;
    s[tid] = v;
    __syncthreads();
    for (int off = 1; off < 1024; off <<= 1) {
        int t2 = (tid >= off) ? s[tid - off] : 0;
        __syncthreads();
        s[tid] += t2;
        __syncthreads();
    }
    if (i < N) rowstart[i] = s[tid] - v;
    if (tid == 1023) bsum[blockIdx.x] = s[1023];
}

__global__ void k_scan2(const int* __restrict__ bsum, int nblk, int* __restrict__ boff) {
    __shared__ int s[128];
    int t = threadIdx.x;
    if (t < nblk) s[t] = bsum[t];
    __syncthreads();
    if (t == 0) {
        int a = 0;
        for (int i = 0; i < nblk; i++) { int v = s[i]; s[i] = a; a += v; }
    }
    __syncthreads();
    if (t < nblk) boff[t] = s[t];
}

__global__ void k_scan3(int N, int E, int* __restrict__ rowstart, const int* __restrict__ boff,
                        const int* __restrict__ cnt, float* __restrict__ invs) {
    int i = blockIdx.x * blockDim.x + threadIdx.x;
    if (i < N) {
        int r = rowstart[i] + boff[i >> 10];
        rowstart[i] = r;
        invs[i] = rsqrtf((float)(1 + cnt[i]));
    }
    if (i == 0 && blockIdx.x == 0) rowstart[N] = E;
}

__global__ void k_fill_r(const int* __restrict__ ei, int E, const int* __restrict__ rowstart,
                         const unsigned* __restrict__ rank, unsigned* __restrict__ recs,
                         const int* __restrict__ flagp) {
    int is64 = *flagp;
    int e = blockIdx.x * blockDim.x + threadIdx.x;
    if (e < E) {
        int d = ld_dst(ei, e, E, is64);
        int s = ld_src(ei, e, E, is64);
        recs[rowstart[d] + rank[e]] = (unsigned)s;
    }
}

__global__ void k_agg_f32(const float* __restrict__ x, const int* __restrict__ rowstart,
                          const float* __restrict__ invs, const unsigned* __restrict__ recs,
                          int N, float* __restrict__ aggOut) {
    int node = blockIdx.x * 4 + (threadIdx.x >> 6);
    int lane = threadIdx.x & 63;
    if (node >= N) return;
    const float2* xr = (const float2*)x;
    float wn = invs[node];
    float2 xself = xr[(size_t)node * 64 + lane];
    float accx = wn * xself.x, accy = wn * xself.y;
    int e = rowstart[node], e1 = rowstart[node + 1];
    for (; e < e1; ++e) {
        unsigned s = recs[e];
        float w = invs[s];
        float2 v = xr[(size_t)s * 64 + lane];
        accx = fmaf(w, v.x, accx); accy = fmaf(w, v.y, accy);
    }
    float2 o; o.x = accx * wn; o.y = accy * wn;
    ((float2*)aggOut)[(size_t)node * 64 + lane] = o;
}

#define GROWS 32
__global__ __launch_bounds__(128) void k_gemm_f32(float* __restrict__ out, const float* __restrict__ Wm,
                                                  const float* __restrict__ bb,
                                                  const float* __restrict__ x, int N) {
    __shared__ float Ws[64 * DD];
    __shared__ float As[DD * GROWS];
    int t = threadIdx.x;
    int rowBase = blockIdx.x * GROWS;
    {
        int r = t & 31, kq = t >> 5;
        if (rowBase + r < N) {
            const float4* Av = (const float4*)(out + (size_t)(rowBase + r) * DD);
            #pragma unroll
            for (int q = 0; q < 8; q++) {
                float4 v = Av[kq * 8 + q];
                int k = (kq * 8 + q) * 4;
                As[(k + 0) * GROWS + r] = v.x;
                As[(k + 1) * GROWS + r] = v.y;
                As[(k + 2) * GROWS + r] = v.z;
                As[(k + 3) * GROWS + r] = v.w;
            }
        } else {
            #pragma unroll
            for (int q = 0; q < 8; q++) {
                int k = (kq * 8 + q) * 4;
                As[(k + 0) * GROWS + r] = 0.f;
                As[(k + 1) * GROWS + r] = 0.f;
                As[(k + 2) * GROWS + r] = 0.f;
                As[(k + 3) * GROWS + r] = 0.f;
            }
        }
    }
    int tx = t & 15, ty = t >> 4;
    int c0 = tx * 8, r0 = ty * 4;
    float acc[4][8];
    #pragma unroll
    for (int i = 0; i < 4; i++)
        #pragma unroll
        for (int j = 0; j < 8; j++) acc[i][j] = 0.f;
    for (int kk = 0; kk < DD; kk += 64) {
        __syncthreads();
        const float4* Wv = (const float4*)(Wm + (size_t)kk * DD);
        #pragma unroll
        for (int i = 0; i < 16; i++) ((float4*)Ws)[t + i * 128] = Wv[t + i * 128];
        __syncthreads();
        #pragma unroll 4
        for (int k = 0; k < 64; k++) {
            const float4 a = *(const float4*)&As[(kk + k) * GROWS + r0];
            const float4 w0 = *(const float4*)&Ws[k * DD + c0];
            const float4 w1 = *(const float4*)&Ws[k * DD + c0 + 4];
            const float av[4] = {a.x, a.y, a.z, a.w};
            const float wv[8] = {w0.x, w0.y, w0.z, w0.w, w1.x, w1.y, w1.z, w1.w};
            #pragma unroll
            for (int i = 0; i < 4; i++)
                #pragma unroll
                for (int j = 0; j < 8; j++) acc[i][j] = fmaf(av[i], wv[j], acc[i][j]);
        }
    }
    float bv[8];
    {
        float4 b0 = *(const float4*)&bb[c0];
        float4 b1 = *(const float4*)&bb[c0 + 4];
        bv[0] = b0.x; bv[1] = b0.y; bv[2] = b0.z; bv[3] = b0.w;
        bv[4] = b1.x; bv[5] = b1.y; bv[6] = b1.z; bv[7] = b1.w;
    }
    #pragma unroll
    for (int i = 0; i < 4; i++) {
        int row = rowBase + r0 + i;
        if (row < N) {
            const float4 xv0 = *(const float4*)&x[(size_t)row * DD + c0];
            const float4 xv1 = *(const float4*)&x[(size_t)row * DD + c0 + 4];
            float4 o0, o1;
            o0.x = fmaxf(acc[i][0] + bv[0], 0.f) + xv0.x;
            o0.y = fmaxf(acc[i][1] + bv[1], 0.f) + xv0.y;
            o0.z = fmaxf(acc[i][2] + bv[2], 0.f) + xv0.z;
            o0.w = fmaxf(acc[i][3] + bv[3], 0.f) + xv0.w;
            o1.x = fmaxf(acc[i][4] + bv[4], 0.f) + xv1.x;
            o1.y = fmaxf(acc[i][5] + bv[5], 0.f) + xv1.y;
            o1.z = fmaxf(acc[i][6] + bv[6], 0.f) + xv1.z;
            o1.w = fmaxf(acc[i][7] + bv[7], 0.f) + xv1.w;
            *(float4*)&out[(size_t)row * DD + c0] = o0;
            *(float4*)&out[(size_t)row * DD + c0 + 4] = o1;
        }
    }
}

extern "C" void kernel_launch(void* const* d_in, const int* in_sizes, int n_in,
                              void* d_out, int out_size, void* d_ws, size_t ws_size,
                              hipStream_t stream) {
    const float* x = (const float*)d_in[0];
    const float* W = (const float*)d_in[1];
    const float* b = (const float*)d_in[2];
    const int*   ei = (const int*)d_in[3];
    int N = in_sizes[0] / DD;
    int E = in_sizes[3] / 2;
    float* out = (float*)d_out;
    float* outTail = out + (size_t)N * DD;

    int NB = (N + 511) >> BSH;          // buckets of 512 nodes
    int nA = (E + EPB - 1) / EPB;       // A-pass blocks

    // new-path workspace layout
    char* wsb = (char*)d_ws;
    size_t off = 0;
    unsigned* brec = (unsigned*)(wsb + off);  off += (size_t)E * 4;
    unsigned* recs = (unsigned*)(wsb + off);  off += (size_t)E * 4;
    unsigned* xs   = (unsigned*)(wsb + off);  off += (size_t)N * 64 * 4;
    ushort*   Wt   = (ushort*)(wsb + off);    off += (size_t)DD * DD * 2;
    int* H         = (int*)(wsb + off);       off += (size_t)nA * NB * 4;
    int* colsum    = (int*)(wsb + off);       off += (size_t)NB * 4;
    int* rowstart  = (int*)(wsb + off);       off += (size_t)(N + 1) * 4;
    float* invs    = (float*)(wsb + off);     off += (size_t)N * 4;

    bool newpath = (ws_size >= off) && (NB <= 256) && (nA <= 1024) && (N <= 131072) && (E >= 64);

    if (newpath) {
        kA1<<<nA + 64, 256, 0, stream>>>(ei, E, NB, nA, outTail, H, W, Wt);
        k_scanH1<<<NB, 256, 0, stream>>>(H, nA, NB, colsum);
        kA2<<<nA, 256, 0, stream>>>(ei, E, NB, H, colsum, brec);
        kB<<<NB, 256, 0, stream>>>(brec, colsum, NB, N, E, recs, rowstart, invs);
        int n2 = N * 64;
        k_cvt_xs<<<(n2 + 255) / 256, 256, 0, stream>>>((const float2*)x, invs, xs, n2);
        k_agg_gemm<<<(N + 63) / 64, 256, 0, stream>>>(xs, rowstart, invs, recs, Wt, b, x, out, N);
    } else {
        // fallback: rank-based build + f32 compute (known good)
        off = 0;
        unsigned* recsF = (unsigned*)(wsb + off);  off += (size_t)E * 4;
        unsigned* rank  = (unsigned*)(wsb + off);  off += (size_t)E * 4;
        int* cnt        = (int*)(wsb + off);       off += (size_t)N * 4;
        int* rowstartF  = (int*)(wsb + off);       off += (size_t)(N + 1) * 4;
        float* invsF    = (float*)(wsb + off);     off += (size_t)N * 4;
        int* bsum       = (int*)(wsb + off);       off += 512 * 4;
        int* boff       = (int*)(wsb + off);       off += 512 * 4;
        int* flagF      = (int*)(wsb + off);

        hipMemsetAsync(cnt, 0, sizeof(int) * (size_t)N, stream);
        k_sniff<<<1, 1024, 0, stream>>>(ei, 1024, flagF);
        k_count_echo<<<(E + 255) / 256, 256, 0, stream>>>(ei, E, cnt, outTail, rank, flagF);
        int nblk = (N + 1023) / 1024;
        k_scan1<<<nblk, 1024, 0, stream>>>(cnt, N, rowstartF, bsum);
        k_scan2<<<1, 128, 0, stream>>>(bsum, nblk, boff);
        k_scan3<<<(N + 255) / 256, 256, 0, stream>>>(N, E, rowstartF, boff, cnt, invsF);
        k_fill_r<<<(E + 255) / 256, 256, 0, stream>>>(ei, E, rowstartF, rank, recsF, flagF);
        k_agg_f32<<<(N + 3) / 4, 256, 0, stream>>>(x, rowstartF, invsF, recsF, N, out);
        k_gemm_f32<<<(N + GROWS - 1) / GROWS, 128, 0, stream>>>(out, W, b, x, N);
    }
}

// Round 10
// 249.892 us; speedup vs baseline: 1.3059x; 1.3059x over previous
//
#include <hip/hip_runtime.h>

// GCNBlock: out0 = relu( (D^-1/2 (A+I) D^-1/2) (x W) + b ) + x   [N,128] f32
//           out1 = edge_index echoed (as float values) appended in d_out
// Identity: Agg(xW) = Agg(x) W.
// Round 10: REVERT round-9's agg+gemm fusion (killed gather occupancy:
// 25000->1563 blocks, occ 66->25%, HBM 3.1->1.38 TB/s, 70->195us).
// Keep round-9's consolidated CSR build (7 launches): kA1(+cvtW, inline
// sniff, nt-stores), scanH1, kA2(local colsum scan), kB, cvt_xs,
// then round-8's separate k_agg_s (1 wave/node) + swapped-operand MFMA gemm.

#define DD 128
#define EPB 2048      // edges per A-block (8 iters x 256 threads)
#define BSH 9         // bucket shift: 512 nodes per bucket
typedef __attribute__((ext_vector_type(8))) short bf16x8;
typedef __attribute__((ext_vector_type(4))) float f32x4;

__device__ __forceinline__ ushort f2bf(float f) {
    unsigned u = __float_as_uint(f);
    unsigned r = (u + 0x7fffu + ((u >> 16) & 1u)) >> 16;  // RNE
    return (ushort)r;
}
__device__ __forceinline__ float bflo(unsigned u) { return __uint_as_float(u << 16); }
__device__ __forceinline__ float bfhi(unsigned u) { return __uint_as_float(u & 0xffff0000u); }

__device__ __forceinline__ int ld_src(const int* p, int e, int E, int is64) {
    return is64 ? p[2 * e] : p[e];
}
__device__ __forceinline__ int ld_dst(const int* p, int e, int E, int is64) {
    return is64 ? p[2 * (E + e)] : p[E + e];
}

// inline dtype sniff: int64 edge data has all-zero high words.
// Every wave reads the SAME first 128 ints (L2-hot) -> identical result.
__device__ __forceinline__ int detect64(const int* __restrict__ p, int E) {
    int lane = threadIdx.x & 63;
    int idx = 2 * lane + 1;
    if (idx >= 2 * E) idx = 2 * E - 1;
    unsigned long long m = __ballot(p[idx] != 0);
    return m == 0ull ? 1 : 0;
}

// ---------- A1: bucket histogram + fused echo (+ tail blocks convert W) ----------
__global__ __launch_bounds__(256) void kA1(const int* __restrict__ ei, int E, int NB, int nA,
                                           float* __restrict__ outTail, int* __restrict__ H,
                                           const float* __restrict__ W, ushort* __restrict__ Wt) {
    int t = threadIdx.x, a = blockIdx.x;
    if (a >= nA) {  // W-conversion tail blocks
        int i = (a - nA) * 256 + t;
        if (i < DD * DD) {
            int c = i >> 7, k = i & 127;
            Wt[i] = f2bf(W[k * DD + c]);
        }
        return;
    }
    __shared__ int hist[256];
    int is64 = detect64(ei, E);
    if (t < NB) hist[t] = 0;
    __syncthreads();
    int base = a * EPB;
    #pragma unroll
    for (int it = 0; it < EPB / 256; ++it) {
        int e = base + it * 256 + t;
        if (e < E) {
            int s = ld_src(ei, e, E, is64);
            int d = ld_dst(ei, e, E, is64);
            __builtin_nontemporal_store((float)s, &outTail[e]);
            __builtin_nontemporal_store((float)d, &outTail[E + e]);
            atomicAdd(&hist[d >> BSH], 1);
        }
    }
    __syncthreads();
    if (t < NB) H[a * NB + t] = hist[t];
}

// ---------- scanH1: per-column exclusive scan of H (NB blocks, nA<=1024) ----------
__global__ __launch_bounds__(256) void k_scanH1(int* __restrict__ H, int nA, int NB,
                                                int* __restrict__ colsum) {
    __shared__ int s[256];
    int b = blockIdx.x, t = threadIdx.x;
    int K = (nA + 255) / 256;
    int base = t * K;
    int local = 0;
    for (int j = 0; j < K; ++j) {
        int a = base + j;
        if (a < nA) local += H[a * NB + b];
    }
    s[t] = local;
    __syncthreads();
    #pragma unroll
    for (int off = 1; off < 256; off <<= 1) {
        int u = (t >= off) ? s[t - off] : 0;
        __syncthreads();
        s[t] += u;
        __syncthreads();
    }
    int run = s[t] - local;  // exclusive prefix of this thread's chunk
    for (int j = 0; j < K; ++j) {
        int a = base + j;
        if (a < nA) { int v = H[a * NB + b]; H[a * NB + b] = run; run += v; }
    }
    if (t == 255) colsum[b] = s[255];
}

// ---------- A2: scatter packed records; bucketstart derived locally from colsum ----
// record = src | (dst&511)<<17   (needs N <= 131072)
__global__ __launch_bounds__(256) void kA2(const int* __restrict__ ei, int E, int NB,
                                           const int* __restrict__ H,
                                           const int* __restrict__ colsum,
                                           unsigned* __restrict__ brec) {
    __shared__ int bs[256];
    __shared__ int cur[256];
    int t = threadIdx.x, a = blockIdx.x;
    int is64 = detect64(ei, E);
    int v = (t < NB) ? colsum[t] : 0;
    bs[t] = v;
    __syncthreads();
    #pragma unroll
    for (int off = 1; off < 256; off <<= 1) {
        int u = (t >= off) ? bs[t - off] : 0;
        __syncthreads();
        bs[t] += u;
        __syncthreads();
    }
    if (t < NB) cur[t] = H[a * NB + t] + bs[t] - v;  // exclusive bucketstart + block offset
    __syncthreads();
    int base = a * EPB;
    #pragma unroll
    for (int it = 0; it < EPB / 256; ++it) {
        int e = base + it * 256 + t;
        if (e < E) {
            int s = ld_src(ei, e, E, is64);
            int d = ld_dst(ei, e, E, is64);
            int pos = atomicAdd(&cur[d >> BSH], 1);  // LDS atomic
            __builtin_nontemporal_store((unsigned)s | ((unsigned)(d & 511) << 17), &brec[pos]);
        }
    }
}

// ---------- B: per-bucket CSR finalize: recs + rowstart + invs ----------
__global__ __launch_bounds__(256) void kB(const unsigned* __restrict__ brec,
                                          const int* __restrict__ colsum, int NB, int N,
                                          int E, unsigned* __restrict__ recs,
                                          int* __restrict__ rowstart, float* __restrict__ invs) {
    __shared__ int bs[256];
    __shared__ int hist[512];
    __shared__ int scan[513];
    __shared__ int cur[512];
    int b = blockIdx.x, t = threadIdx.x;
    int v = (t < NB) ? colsum[t] : 0;
    bs[t] = v;
    __syncthreads();
    #pragma unroll
    for (int off = 1; off < 256; off <<= 1) {
        int u = (t >= off) ? bs[t - off] : 0;
        __syncthreads();
        bs[t] += u;
        __syncthreads();
    }
    if (t < NB) bs[t] -= v;  // exclusive
    hist[t] = 0; hist[t + 256] = 0;
    __syncthreads();
    int lo = bs[b], hi = lo + colsum[b];
    for (int i = lo + t; i < hi; i += 256) atomicAdd(&hist[brec[i] >> 17], 1);
    __syncthreads();
    if (t == 0) {
        int acc = 0;
        for (int j = 0; j < 512; ++j) { scan[j] = acc; acc += hist[j]; }
        scan[512] = acc;
    }
    __syncthreads();
    int nodeBase = b << BSH;
    #pragma unroll
    for (int j = t; j < 512; j += 256) {
        int node = nodeBase + j;
        if (node < N) {
            rowstart[node] = lo + scan[j];
            invs[node] = rsqrtf((float)(1 + hist[j]));  // deg includes self-loop
        }
        cur[j] = lo + scan[j];
    }
    if (b == NB - 1 && t == 0) rowstart[N] = E;
    __syncthreads();
    for (int i = lo + t; i < hi; i += 256) {
        unsigned r = brec[i];
        int pos = atomicAdd(&cur[r >> 17], 1);  // LDS atomic
        __builtin_nontemporal_store(r & 0x1FFFFu, &recs[pos]);
    }
}

// ---------- convert x -> bf16 pre-scaled by invs: xs[i] = bf16(invs[node]*x[i]) ----------
__global__ void k_cvt_xs(const float2* __restrict__ x2, const float* __restrict__ invs,
                         unsigned* __restrict__ xs, int n2) {
    int i = blockIdx.x * blockDim.x + threadIdx.x;
    if (i < n2) {
        float w = invs[i >> 6];
        float2 v = x2[i];
        xs[i] = (unsigned)f2bf(w * v.x) | ((unsigned)f2bf(w * v.y) << 16);
    }
}

// ---------- aggregation: 1 wave/node; deep-unrolled gather of pre-scaled bf16 rows ----------
__global__ void k_agg_s(const unsigned* __restrict__ xs, const int* __restrict__ rowstart,
                        const float* __restrict__ invs, const unsigned* __restrict__ recs,
                        int N, unsigned* __restrict__ aggh) {
    int node = blockIdx.x * 4 + (threadIdx.x >> 6);
    int lane = threadIdx.x & 63;
    if (node >= N) return;
    float wn = invs[node];
    unsigned us = xs[(size_t)node * 64 + lane];  // self: xs[node]*wn = invs^2 * x
    float accx = bflo(us), accy = bfhi(us);
    int e = rowstart[node], e1 = rowstart[node + 1];
    for (; e + 16 <= e1; e += 16) {
        unsigned sv[16], vv[16];
        #pragma unroll
        for (int j = 0; j < 16; ++j) sv[j] = recs[e + j];
        #pragma unroll
        for (int j = 0; j < 16; ++j) vv[j] = xs[(size_t)sv[j] * 64 + lane];
        #pragma unroll
        for (int j = 0; j < 16; ++j) { accx += bflo(vv[j]); accy += bfhi(vv[j]); }
    }
    if (e + 8 <= e1) {
        unsigned sv[8], vv[8];
        #pragma unroll
        for (int j = 0; j < 8; ++j) sv[j] = recs[e + j];
        #pragma unroll
        for (int j = 0; j < 8; ++j) vv[j] = xs[(size_t)sv[j] * 64 + lane];
        #pragma unroll
        for (int j = 0; j < 8; ++j) { accx += bflo(vv[j]); accy += bfhi(vv[j]); }
        e += 8;
    }
    for (; e < e1; ++e) {
        unsigned v0 = xs[(size_t)recs[e] * 64 + lane];
        accx += bflo(v0); accy += bfhi(v0);
    }
    float ox = accx * wn, oy = accy * wn;
    aggh[(size_t)node * 64 + lane] = (unsigned)f2bf(ox) | ((unsigned)f2bf(oy) << 16);
}

// ---------- MFMA GEMM + bias + relu + residual (swapped operands) ----------
// D = mfma(A=Wt_frag, B=agg_frag):
//   A frag: m=lane&15 (W col within 16-group), k=(lane>>4)*8+j  -> Wt[c][k] contig
//   B frag: n=lane&15 (node row),             k=(lane>>4)*8+j  -> aggh[r][k] contig
//   C/D:    col=lane&15 -> NODE row; row=(lane>>4)*4+reg -> 4 CONSECUTIVE out cols
// => each lane's f32x4 acc = float4 at out[node][n*16+(lane>>4)*4]
__global__ __launch_bounds__(256) void k_gemm_mfma(const ushort* __restrict__ aggh,
                                                   const ushort* __restrict__ Wt,
                                                   const float* __restrict__ bb,
                                                   const float* __restrict__ x,
                                                   float* __restrict__ out, int N) {
    int wave = threadIdx.x >> 6, lane = threadIdx.x & 63;
    int rowBase = blockIdx.x * 64 + wave * 16;
    int rfrag = lane & 15, kgrp = lane >> 4;
    f32x4 zero = {0.f, 0.f, 0.f, 0.f};
    f32x4 acc[8];
    #pragma unroll
    for (int n = 0; n < 8; ++n) acc[n] = zero;

    int arow = rowBase + rfrag;
    bool av = arow < N;
    const ushort* bbase = aggh + (size_t)(av ? arow : 0) * DD + kgrp * 8;  // B frag (nodes)
    const ushort* wbase = Wt + rfrag * DD + kgrp * 8;                      // A frag (W cols)

    #pragma unroll
    for (int ks = 0; ks < 4; ++ks) {
        bf16x8 bnode = {0, 0, 0, 0, 0, 0, 0, 0};
        if (av) bnode = *(const bf16x8*)(bbase + ks * 32);
        #pragma unroll
        for (int n = 0; n < 8; ++n) {
            bf16x8 aw = *(const bf16x8*)(wbase + n * 16 * DD + ks * 32);
            acc[n] = __builtin_amdgcn_mfma_f32_16x16x32_bf16(aw, bnode, acc[n], 0, 0, 0);
        }
    }

    int node = rowBase + (lane & 15);
    if (node < N) {
        int csub = (lane >> 4) * 4;
        #pragma unroll
        for (int n = 0; n < 8; ++n) {
            int c0 = n * 16 + csub;
            float4 bv = *(const float4*)&bb[c0];
            float4 xv = *(const float4*)&x[(size_t)node * DD + c0];
            float4 o;
            o.x = fmaxf(acc[n][0] + bv.x, 0.f) + xv.x;
            o.y = fmaxf(acc[n][1] + bv.y, 0.f) + xv.y;
            o.z = fmaxf(acc[n][2] + bv.z, 0.f) + xv.z;
            o.w = fmaxf(acc[n][3] + bv.w, 0.f) + xv.w;
            *(float4*)&out[(size_t)node * DD + c0] = o;
        }
    }
}

// =================== fallback path (shape/ws outside new-path limits) ===================
__global__ void k_sniff(const int* __restrict__ p, int n_check, int* __restrict__ flag) {
    __shared__ int any_nonzero;
    if (threadIdx.x == 0) any_nonzero = 0;
    __syncthreads();
    int j = threadIdx.x;
    if (j < n_check && p[2 * j + 1] != 0) any_nonzero = 1;
    __syncthreads();
    if (threadIdx.x == 0) *flag = any_nonzero ? 0 : 1;
}

__global__ void k_count_echo(const int* __restrict__ ei, int E, int* __restrict__ cnt,
                             float* __restrict__ outTail, unsigned* __restrict__ rank,
                             const int* __restrict__ flagp) {
    int is64 = *flagp;
    int e = blockIdx.x * blockDim.x + threadIdx.x;
    if (e < E) {
        int s = ld_src(ei, e, E, is64);
        int d = ld_dst(ei, e, E, is64);
        outTail[e] = (float)s;
        outTail[E + e] = (float)d;
        rank[e] = (unsigned)atomicAdd(&cnt[d], 1);
    }
}

__global__ void k_scan1(const int* __restrict__ cnt, int N, int* __restrict__ rowstart,
                        int* __restrict__ bsum) {
    __shared__ int s[1024];
    int tid = threadIdx.x;
    int i = blockIdx.x * 1024 + tid;
    int v = (i < N) ? cnt[i] : 0;
    s[tid] = v;
    __syncthreads();
    for (int off = 1; off < 1024; off <<= 1) {
        int t2 = (tid >= off) ? s[tid - off] : 0;
        __syncthreads();
        s[tid] += t2;
        __syncthreads();
    }
    if (i < N) rowstart[i] = s[tid] - v;
    if (tid == 1023) bsum[blockIdx.x] = s[1023];
}

__global__ void k_scan2(const int* __restrict__ bsum, int nblk, int* __restrict__ boff) {
    __shared__ int s[128];
    int t = threadIdx.x;
    if (t < nblk) s[t] = bsum[t];
    __syncthreads();
    if (t == 0) {
        int a = 0;
        for (int i = 0; i < nblk; i++) { int v = s[i]; s[i] = a; a += v; }
    }
    __syncthreads();
    if (t < nblk) boff[t] = s[t];
}

__global__ void k_scan3(int N, int E, int* __restrict__ rowstart, const int* __restrict__ boff,
                        const int* __restrict__ cnt, float* __restrict__ invs) {
    int i = blockIdx.x * blockDim.x + threadIdx.x;
    if (i < N) {
        int r = rowstart[i] + boff[i >> 10];
        rowstart[i] = r;
        invs[i] = rsqrtf((float)(1 + cnt[i]));
    }
    if (i == 0 && blockIdx.x == 0) rowstart[N] = E;
}

__global__ void k_fill_r(const int* __restrict__ ei, int E, const int* __restrict__ rowstart,
                         const unsigned* __restrict__ rank, unsigned* __restrict__ recs,
                         const int* __restrict__ flagp) {
    int is64 = *flagp;
    int e = blockIdx.x * blockDim.x + threadIdx.x;
    if (e < E) {
        int d = ld_dst(ei, e, E, is64);
        int s = ld_src(ei, e, E, is64);
        recs[rowstart[d] + rank[e]] = (unsigned)s;
    }
}

__global__ void k_agg_f32(const float* __restrict__ x, const int* __restrict__ rowstart,
                          const float* __restrict__ invs, const unsigned* __restrict__ recs,
                          int N, float* __restrict__ aggOut) {
    int node = blockIdx.x * 4 + (threadIdx.x >> 6);
    int lane = threadIdx.x & 63;
    if (node >= N) return;
    const float2* xr = (const float2*)x;
    float wn = invs[node];
    float2 xself = xr[(size_t)node * 64 + lane];
    float accx = wn * xself.x, accy = wn * xself.y;
    int e = rowstart[node], e1 = rowstart[node + 1];
    for (; e < e1; ++e) {
        unsigned s = recs[e];
        float w = invs[s];
        float2 v = xr[(size_t)s * 64 + lane];
        accx = fmaf(w, v.x, accx); accy = fmaf(w, v.y, accy);
    }
    float2 o; o.x = accx * wn; o.y = accy * wn;
    ((float2*)aggOut)[(size_t)node * 64 + lane] = o;
}

#define GROWS 32
__global__ __launch_bounds__(128) void k_gemm_f32(float* __restrict__ out, const float* __restrict__ Wm,
                                                  const float* __restrict__ bb,
                                                  const float* __restrict__ x, int N) {
    __shared__ float Ws[64 * DD];
    __shared__ float As[DD * GROWS];
    int t = threadIdx.x;
    int rowBase = blockIdx.x * GROWS;
    {
        int r = t & 31, kq = t >> 5;
        if (rowBase + r < N) {
            const float4* Av = (const float4*)(out + (size_t)(rowBase + r) * DD);
            #pragma unroll
            for (int q = 0; q < 8; q++) {
                float4 v = Av[kq * 8 + q];
                int k = (kq * 8 + q) * 4;
                As[(k + 0) * GROWS + r] = v.x;
                As[(k + 1) * GROWS + r] = v.y;
                As[(k + 2) * GROWS + r] = v.z;
                As[(k + 3) * GROWS + r] = v.w;
            }
        } else {
            #pragma unroll
            for (int q = 0; q < 8; q++) {
                int k = (kq * 8 + q) * 4;
                As[(k + 0) * GROWS + r] = 0.f;
                As[(k + 1) * GROWS + r] = 0.f;
                As[(k + 2) * GROWS + r] = 0.f;
                As[(k + 3) * GROWS + r] = 0.f;
            }
        }
    }
    int tx = t & 15, ty = t >> 4;
    int c0 = tx * 8, r0 = ty * 4;
    float acc[4][8];
    #pragma unroll
    for (int i = 0; i < 4; i++)
        #pragma unroll
        for (int j = 0; j < 8; j++) acc[i][j] = 0.f;
    for (int kk = 0; kk < DD; kk += 64) {
        __syncthreads();
        const float4* Wv = (const float4*)(Wm + (size_t)kk * DD);
        #pragma unroll
        for (int i = 0; i < 16; i++) ((float4*)Ws)[t + i * 128] = Wv[t + i * 128];
        __syncthreads();
        #pragma unroll 4
        for (int k = 0; k < 64; k++) {
            const float4 a = *(const float4*)&As[(kk + k) * GROWS + r0];
            const float4 w0 = *(const float4*)&Ws[k * DD + c0];
            const float4 w1 = *(const float4*)&Ws[k * DD + c0 + 4];
            const float av[4] = {a.x, a.y, a.z, a.w};
            const float wv[8] = {w0.x, w0.y, w0.z, w0.w, w1.x, w1.y, w1.z, w1.w};
            #pragma unroll
            for (int i = 0; i < 4; i++)
                #pragma unroll
                for (int j = 0; j < 8; j++) acc[i][j] = fmaf(av[i], wv[j], acc[i][j]);
        }
    }
    float bv[8];
    {
        float4 b0 = *(const float4*)&bb[c0];
        float4 b1 = *(const float4*)&bb[c0 + 4];
        bv[0] = b0.x; bv[1] = b0.y; bv[2] = b0.z; bv[3] = b0.w;
        bv[4] = b1.x; bv[5] = b1.y; bv[6] = b1.z; bv[7] = b1.w;
    }
    #pragma unroll
    for (int i = 0; i < 4; i++) {
        int row = rowBase + r0 + i;
        if (row < N) {
            const float4 xv0 = *(const float4*)&x[(size_t)row * DD + c0];
            const float4 xv1 = *(const float4*)&x[(size_t)row * DD + c0 + 4];
            float4 o0, o1;
            o0.x = fmaxf(acc[i][0] + bv[0], 0.f) + xv0.x;
            o0.y = fmaxf(acc[i][1] + bv[1], 0.f) + xv0.y;
            o0.z = fmaxf(acc[i][2] + bv[2], 0.f) + xv0.z;
            o0.w = fmaxf(acc[i][3] + bv[3], 0.f) + xv0.w;
            o1.x = fmaxf(acc[i][4] + bv[4], 0.f) + xv1.x;
            o1.y = fmaxf(acc[i][5] + bv[5], 0.f) + xv1.y;
            o1.z = fmaxf(acc[i][6] + bv[6], 0.f) + xv1.z;
            o1.w = fmaxf(acc[i][7] + bv[7], 0.f) + xv1.w;
            *(float4*)&out[(size_t)row * DD + c0] = o0;
            *(float4*)&out[(size_t)row * DD + c0 + 4] = o1;
        }
    }
}

extern "C" void kernel_launch(void* const* d_in, const int* in_sizes, int n_in,
                              void* d_out, int out_size, void* d_ws, size_t ws_size,
                              hipStream_t stream) {
    const float* x = (const float*)d_in[0];
    const float* W = (const float*)d_in[1];
    const float* b = (const float*)d_in[2];
    const int*   ei = (const int*)d_in[3];
    int N = in_sizes[0] / DD;
    int E = in_sizes[3] / 2;
    float* out = (float*)d_out;
    float* outTail = out + (size_t)N * DD;

    int NB = (N + 511) >> BSH;          // buckets of 512 nodes
    int nA = (E + EPB - 1) / EPB;       // A-pass blocks

    // new-path workspace layout
    char* wsb = (char*)d_ws;
    size_t off = 0;
    unsigned* brec = (unsigned*)(wsb + off);  off += (size_t)E * 4;
    unsigned* recs = (unsigned*)(wsb + off);  off += (size_t)E * 4;
    unsigned* xs   = (unsigned*)(wsb + off);  off += (size_t)N * 64 * 4;
    unsigned* aggh = (unsigned*)(wsb + off);  off += (size_t)N * 64 * 4;
    ushort*   Wt   = (ushort*)(wsb + off);    off += (size_t)DD * DD * 2;
    int* H         = (int*)(wsb + off);       off += (size_t)nA * NB * 4;
    int* colsum    = (int*)(wsb + off);       off += (size_t)NB * 4;
    int* rowstart  = (int*)(wsb + off);       off += (size_t)(N + 1) * 4;
    float* invs    = (float*)(wsb + off);     off += (size_t)N * 4;

    bool newpath = (ws_size >= off) && (NB <= 256) && (nA <= 1024) && (N <= 131072) && (E >= 64);

    if (newpath) {
        kA1<<<nA + 64, 256, 0, stream>>>(ei, E, NB, nA, outTail, H, W, Wt);
        k_scanH1<<<NB, 256, 0, stream>>>(H, nA, NB, colsum);
        kA2<<<nA, 256, 0, stream>>>(ei, E, NB, H, colsum, brec);
        kB<<<NB, 256, 0, stream>>>(brec, colsum, NB, N, E, recs, rowstart, invs);
        int n2 = N * 64;
        k_cvt_xs<<<(n2 + 255) / 256, 256, 0, stream>>>((const float2*)x, invs, xs, n2);
        k_agg_s<<<(N + 3) / 4, 256, 0, stream>>>(xs, rowstart, invs, recs, N, aggh);
        k_gemm_mfma<<<(N + 63) / 64, 256, 0, stream>>>((const ushort*)aggh, Wt, b, x, out, N);
    } else {
        // fallback: rank-based build + f32 compute (known good)
        off = 0;
        unsigned* recsF = (unsigned*)(wsb + off);  off += (size_t)E * 4;
        unsigned* rank  = (unsigned*)(wsb + off);  off += (size_t)E * 4;
        int* cnt        = (int*)(wsb + off);       off += (size_t)N * 4;
        int* rowstartF  = (int*)(wsb + off);       off += (size_t)(N + 1) * 4;
        float* invsF    = (float*)(wsb + off);     off += (size_t)N * 4;
        int* bsum       = (int*)(wsb + off);       off += 512 * 4;
        int* boff       = (int*)(wsb + off);       off += 512 * 4;
        int* flagF      = (int*)(wsb + off);

        hipMemsetAsync(cnt, 0, sizeof(int) * (size_t)N, stream);
        k_sniff<<<1, 1024, 0, stream>>>(ei, 1024, flagF);
        k_count_echo<<<(E + 255) / 256, 256, 0, stream>>>(ei, E, cnt, outTail, rank, flagF);
        int nblk = (N + 1023) / 1024;
        k_scan1<<<nblk, 1024, 0, stream>>>(cnt, N, rowstartF, bsum);
        k_scan2<<<1, 128, 0, stream>>>(bsum, nblk, boff);
        k_scan3<<<(N + 255) / 256, 256, 0, stream>>>(N, E, rowstartF, boff, cnt, invsF);
        k_fill_r<<<(E + 255) / 256, 256, 0, stream>>>(ei, E, rowstartF, rank, recsF, flagF);
        k_agg_f32<<<(N + 3) / 4, 256, 0, stream>>>(x, rowstartF, invsF, recsF, N, out);
        k_gemm_f32<<<(N + GROWS - 1) / GROWS, 128, 0, stream>>>(out, W, b, x, N);
    }
}

// Round 11
// 183.475 us; speedup vs baseline: 1.7786x; 1.3620x over previous
//
#include <hip/hip_runtime.h>

// GCNBlock: out0 = relu( (D^-1/2 (A+I) D^-1/2) (x W) + b ) + x   [N,128] f32
//           out1 = edge_index echoed (as float values) appended in d_out
// Identity: Agg(xW) = Agg(x) W.
// Round 11: A/B vs round 10 — REMOVE all __builtin_nontemporal_store.
// Scattered 4B record writes need L2 write-combining; NT hint defeated it
// (suspected +60us build regression round 8 -> 10). Everything else identical.

#define DD 128
#define EPB 2048      // edges per A-block (8 iters x 256 threads)
#define BSH 9         // bucket shift: 512 nodes per bucket
typedef __attribute__((ext_vector_type(8))) short bf16x8;
typedef __attribute__((ext_vector_type(4))) float f32x4;

__device__ __forceinline__ ushort f2bf(float f) {
    unsigned u = __float_as_uint(f);
    unsigned r = (u + 0x7fffu + ((u >> 16) & 1u)) >> 16;  // RNE
    return (ushort)r;
}
__device__ __forceinline__ float bflo(unsigned u) { return __uint_as_float(u << 16); }
__device__ __forceinline__ float bfhi(unsigned u) { return __uint_as_float(u & 0xffff0000u); }

__device__ __forceinline__ int ld_src(const int* p, int e, int E, int is64) {
    return is64 ? p[2 * e] : p[e];
}
__device__ __forceinline__ int ld_dst(const int* p, int e, int E, int is64) {
    return is64 ? p[2 * (E + e)] : p[E + e];
}

// inline dtype sniff: int64 edge data has all-zero high words.
// Every wave reads the SAME first 128 ints (L2-hot) -> identical result.
__device__ __forceinline__ int detect64(const int* __restrict__ p, int E) {
    int lane = threadIdx.x & 63;
    int idx = 2 * lane + 1;
    if (idx >= 2 * E) idx = 2 * E - 1;
    unsigned long long m = __ballot(p[idx] != 0);
    return m == 0ull ? 1 : 0;
}

// ---------- A1: bucket histogram + fused echo (+ tail blocks convert W) ----------
__global__ __launch_bounds__(256) void kA1(const int* __restrict__ ei, int E, int NB, int nA,
                                           float* __restrict__ outTail, int* __restrict__ H,
                                           const float* __restrict__ W, ushort* __restrict__ Wt) {
    int t = threadIdx.x, a = blockIdx.x;
    if (a >= nA) {  // W-conversion tail blocks
        int i = (a - nA) * 256 + t;
        if (i < DD * DD) {
            int c = i >> 7, k = i & 127;
            Wt[i] = f2bf(W[k * DD + c]);
        }
        return;
    }
    __shared__ int hist[256];
    int is64 = detect64(ei, E);
    if (t < NB) hist[t] = 0;
    __syncthreads();
    int base = a * EPB;
    #pragma unroll
    for (int it = 0; it < EPB / 256; ++it) {
        int e = base + it * 256 + t;
        if (e < E) {
            int s = ld_src(ei, e, E, is64);
            int d = ld_dst(ei, e, E, is64);
            outTail[e] = (float)s;
            outTail[E + e] = (float)d;
            atomicAdd(&hist[d >> BSH], 1);
        }
    }
    __syncthreads();
    if (t < NB) H[a * NB + t] = hist[t];
}

// ---------- scanH1: per-column exclusive scan of H (NB blocks, nA<=1024) ----------
__global__ __launch_bounds__(256) void k_scanH1(int* __restrict__ H, int nA, int NB,
                                                int* __restrict__ colsum) {
    __shared__ int s[256];
    int b = blockIdx.x, t = threadIdx.x;
    int K = (nA + 255) / 256;
    int base = t * K;
    int local = 0;
    for (int j = 0; j < K; ++j) {
        int a = base + j;
        if (a < nA) local += H[a * NB + b];
    }
    s[t] = local;
    __syncthreads();
    #pragma unroll
    for (int off = 1; off < 256; off <<= 1) {
        int u = (t >= off) ? s[t - off] : 0;
        __syncthreads();
        s[t] += u;
        __syncthreads();
    }
    int run = s[t] - local;  // exclusive prefix of this thread's chunk
    for (int j = 0; j < K; ++j) {
        int a = base + j;
        if (a < nA) { int v = H[a * NB + b]; H[a * NB + b] = run; run += v; }
    }
    if (t == 255) colsum[b] = s[255];
}

// ---------- A2: scatter packed records; bucketstart derived locally from colsum ----
// record = src | (dst&511)<<17   (needs N <= 131072)
__global__ __launch_bounds__(256) void kA2(const int* __restrict__ ei, int E, int NB,
                                           const int* __restrict__ H,
                                           const int* __restrict__ colsum,
                                           unsigned* __restrict__ brec) {
    __shared__ int bs[256];
    __shared__ int cur[256];
    int t = threadIdx.x, a = blockIdx.x;
    int is64 = detect64(ei, E);
    int v = (t < NB) ? colsum[t] : 0;
    bs[t] = v;
    __syncthreads();
    #pragma unroll
    for (int off = 1; off < 256; off <<= 1) {
        int u = (t >= off) ? bs[t - off] : 0;
        __syncthreads();
        bs[t] += u;
        __syncthreads();
    }
    if (t < NB) cur[t] = H[a * NB + t] + bs[t] - v;  // exclusive bucketstart + block offset
    __syncthreads();
    int base = a * EPB;
    #pragma unroll
    for (int it = 0; it < EPB / 256; ++it) {
        int e = base + it * 256 + t;
        if (e < E) {
            int s = ld_src(ei, e, E, is64);
            int d = ld_dst(ei, e, E, is64);
            int pos = atomicAdd(&cur[d >> BSH], 1);  // LDS atomic
            brec[pos] = (unsigned)s | ((unsigned)(d & 511) << 17);
        }
    }
}

// ---------- B: per-bucket CSR finalize: recs + rowstart + invs ----------
__global__ __launch_bounds__(256) void kB(const unsigned* __restrict__ brec,
                                          const int* __restrict__ colsum, int NB, int N,
                                          int E, unsigned* __restrict__ recs,
                                          int* __restrict__ rowstart, float* __restrict__ invs) {
    __shared__ int bs[256];
    __shared__ int hist[512];
    __shared__ int scan[513];
    __shared__ int cur[512];
    int b = blockIdx.x, t = threadIdx.x;
    int v = (t < NB) ? colsum[t] : 0;
    bs[t] = v;
    __syncthreads();
    #pragma unroll
    for (int off = 1; off < 256; off <<= 1) {
        int u = (t >= off) ? bs[t - off] : 0;
        __syncthreads();
        bs[t] += u;
        __syncthreads();
    }
    if (t < NB) bs[t] -= v;  // exclusive
    hist[t] = 0; hist[t + 256] = 0;
    __syncthreads();
    int lo = bs[b], hi = lo + colsum[b];
    for (int i = lo + t; i < hi; i += 256) atomicAdd(&hist[brec[i] >> 17], 1);
    __syncthreads();
    if (t == 0) {
        int acc = 0;
        for (int j = 0; j < 512; ++j) { scan[j] = acc; acc += hist[j]; }
        scan[512] = acc;
    }
    __syncthreads();
    int nodeBase = b << BSH;
    #pragma unroll
    for (int j = t; j < 512; j += 256) {
        int node = nodeBase + j;
        if (node < N) {
            rowstart[node] = lo + scan[j];
            invs[node] = rsqrtf((float)(1 + hist[j]));  // deg includes self-loop
        }
        cur[j] = lo + scan[j];
    }
    if (b == NB - 1 && t == 0) rowstart[N] = E;
    __syncthreads();
    for (int i = lo + t; i < hi; i += 256) {
        unsigned r = brec[i];
        int pos = atomicAdd(&cur[r >> 17], 1);  // LDS atomic
        recs[pos] = r & 0x1FFFFu;
    }
}

// ---------- convert x -> bf16 pre-scaled by invs: xs[i] = bf16(invs[node]*x[i]) ----------
__global__ void k_cvt_xs(const float2* __restrict__ x2, const float* __restrict__ invs,
                         unsigned* __restrict__ xs, int n2) {
    int i = blockIdx.x * blockDim.x + threadIdx.x;
    if (i < n2) {
        float w = invs[i >> 6];
        float2 v = x2[i];
        xs[i] = (unsigned)f2bf(w * v.x) | ((unsigned)f2bf(w * v.y) << 16);
    }
}

// ---------- aggregation: 1 wave/node; deep-unrolled gather of pre-scaled bf16 rows ----------
__global__ void k_agg_s(const unsigned* __restrict__ xs, const int* __restrict__ rowstart,
                        const float* __restrict__ invs, const unsigned* __restrict__ recs,
                        int N, unsigned* __restrict__ aggh) {
    int node = blockIdx.x * 4 + (threadIdx.x >> 6);
    int lane = threadIdx.x & 63;
    if (node >= N) return;
    float wn = invs[node];
    unsigned us = xs[(size_t)node * 64 + lane];  // self: xs[node]*wn = invs^2 * x
    float accx = bflo(us), accy = bfhi(us);
    int e = rowstart[node], e1 = rowstart[node + 1];
    for (; e + 16 <= e1; e += 16) {
        unsigned sv[16], vv[16];
        #pragma unroll
        for (int j = 0; j < 16; ++j) sv[j] = recs[e + j];
        #pragma unroll
        for (int j = 0; j < 16; ++j) vv[j] = xs[(size_t)sv[j] * 64 + lane];
        #pragma unroll
        for (int j = 0; j < 16; ++j) { accx += bflo(vv[j]); accy += bfhi(vv[j]); }
    }
    if (e + 8 <= e1) {
        unsigned sv[8], vv[8];
        #pragma unroll
        for (int j = 0; j < 8; ++j) sv[j] = recs[e + j];
        #pragma unroll
        for (int j = 0; j < 8; ++j) vv[j] = xs[(size_t)sv[j] * 64 + lane];
        #pragma unroll
        for (int j = 0; j < 8; ++j) { accx += bflo(vv[j]); accy += bfhi(vv[j]); }
        e += 8;
    }
    for (; e < e1; ++e) {
        unsigned v0 = xs[(size_t)recs[e] * 64 + lane];
        accx += bflo(v0); accy += bfhi(v0);
    }
    float ox = accx * wn, oy = accy * wn;
    aggh[(size_t)node * 64 + lane] = (unsigned)f2bf(ox) | ((unsigned)f2bf(oy) << 16);
}

// ---------- MFMA GEMM + bias + relu + residual (swapped operands) ----------
// D = mfma(A=Wt_frag, B=agg_frag):
//   A frag: m=lane&15 (W col within 16-group), k=(lane>>4)*8+j  -> Wt[c][k] contig
//   B frag: n=lane&15 (node row),             k=(lane>>4)*8+j  -> aggh[r][k] contig
//   C/D:    col=lane&15 -> NODE row; row=(lane>>4)*4+reg -> 4 CONSECUTIVE out cols
// => each lane's f32x4 acc = float4 at out[node][n*16+(lane>>4)*4]
__global__ __launch_bounds__(256) void k_gemm_mfma(const ushort* __restrict__ aggh,
                                                   const ushort* __restrict__ Wt,
                                                   const float* __restrict__ bb,
                                                   const float* __restrict__ x,
                                                   float* __restrict__ out, int N) {
    int wave = threadIdx.x >> 6, lane = threadIdx.x & 63;
    int rowBase = blockIdx.x * 64 + wave * 16;
    int rfrag = lane & 15, kgrp = lane >> 4;
    f32x4 zero = {0.f, 0.f, 0.f, 0.f};
    f32x4 acc[8];
    #pragma unroll
    for (int n = 0; n < 8; ++n) acc[n] = zero;

    int arow = rowBase + rfrag;
    bool av = arow < N;
    const ushort* bbase = aggh + (size_t)(av ? arow : 0) * DD + kgrp * 8;  // B frag (nodes)
    const ushort* wbase = Wt + rfrag * DD + kgrp * 8;                      // A frag (W cols)

    #pragma unroll
    for (int ks = 0; ks < 4; ++ks) {
        bf16x8 bnode = {0, 0, 0, 0, 0, 0, 0, 0};
        if (av) bnode = *(const bf16x8*)(bbase + ks * 32);
        #pragma unroll
        for (int n = 0; n < 8; ++n) {
            bf16x8 aw = *(const bf16x8*)(wbase + n * 16 * DD + ks * 32);
            acc[n] = __builtin_amdgcn_mfma_f32_16x16x32_bf16(aw, bnode, acc[n], 0, 0, 0);
        }
    }

    int node = rowBase + (lane & 15);
    if (node < N) {
        int csub = (lane >> 4) * 4;
        #pragma unroll
        for (int n = 0; n < 8; ++n) {
            int c0 = n * 16 + csub;
            float4 bv = *(const float4*)&bb[c0];
            float4 xv = *(const float4*)&x[(size_t)node * DD + c0];
            float4 o;
            o.x = fmaxf(acc[n][0] + bv.x, 0.f) + xv.x;
            o.y = fmaxf(acc[n][1] + bv.y, 0.f) + xv.y;
            o.z = fmaxf(acc[n][2] + bv.z, 0.f) + xv.z;
            o.w = fmaxf(acc[n][3] + bv.w, 0.f) + xv.w;
            *(float4*)&out[(size_t)node * DD + c0] = o;
        }
    }
}

// =================== fallback path (shape/ws outside new-path limits) ===================
__global__ void k_sniff(const int* __restrict__ p, int n_check, int* __restrict__ flag) {
    __shared__ int any_nonzero;
    if (threadIdx.x == 0) any_nonzero = 0;
    __syncthreads();
    int j = threadIdx.x;
    if (j < n_check && p[2 * j + 1] != 0) any_nonzero = 1;
    __syncthreads();
    if (threadIdx.x == 0) *flag = any_nonzero ? 0 : 1;
}

__global__ void k_count_echo(const int* __restrict__ ei, int E, int* __restrict__ cnt,
                             float* __restrict__ outTail, unsigned* __restrict__ rank,
                             const int* __restrict__ flagp) {
    int is64 = *flagp;
    int e = blockIdx.x * blockDim.x + threadIdx.x;
    if (e < E) {
        int s = ld_src(ei, e, E, is64);
        int d = ld_dst(ei, e, E, is64);
        outTail[e] = (float)s;
        outTail[E + e] = (float)d;
        rank[e] = (unsigned)atomicAdd(&cnt[d], 1);
    }
}

__global__ void k_scan1(const int* __restrict__ cnt, int N, int* __restrict__ rowstart,
                        int* __restrict__ bsum) {
    __shared__ int s[1024];
    int tid = threadIdx.x;
    int i = blockIdx.x * 1024 + tid;
    int v = (i < N) ? cnt[i] : 0;
    s[tid] = v;
    __syncthreads();
    for (int off = 1; off < 1024; off <<= 1) {
        int t2 = (tid >= off) ? s[tid - off] : 0;
        __syncthreads();
        s[tid] += t2;
        __syncthreads();
    }
    if (i < N) rowstart[i] = s[tid] - v;
    if (tid == 1023) bsum[blockIdx.x] = s[1023];
}

__global__ void k_scan2(const int* __restrict__ bsum, int nblk, int* __restrict__ boff) {
    __shared__ int s[128];
    int t = threadIdx.x;
    if (t < nblk) s[t] = bsum[t];
    __syncthreads();
    if (t == 0) {
        int a = 0;
        for (int i = 0; i < nblk; i++) { int v = s[i]; s[i] = a; a += v; }
    }
    __syncthreads();
    if (t < nblk) boff[t] = s[t];
}

__global__ void k_scan3(int N, int E, int* __restrict__ rowstart, const int* __restrict__ boff,
                        const int* __restrict__ cnt, float* __restrict__ invs) {
    int i = blockIdx.x * blockDim.x + threadIdx.x;
    if (i < N) {
        int r = rowstart[i] + boff[i >> 10];
        rowstart[i] = r;
        invs[i] = rsqrtf((float)(1 + cnt[i]));
    }
    if (i == 0 && blockIdx.x == 0) rowstart[N] = E;
}

__global__ void k_fill_r(const int* __restrict__ ei, int E, const int* __restrict__ rowstart,
                         const unsigned* __restrict__ rank, unsigned* __restrict__ recs,
                         const int* __restrict__ flagp) {
    int is64 = *flagp;
    int e = blockIdx.x * blockDim.x + threadIdx.x;
    if (e < E) {
        int d = ld_dst(ei, e, E, is64);
        int s = ld_src(ei, e, E, is64);
        recs[rowstart[d] + rank[e]] = (unsigned)s;
    }
}

__global__ void k_agg_f32(const float* __restrict__ x, const int* __restrict__ rowstart,
                          const float* __restrict__ invs, const unsigned* __restrict__ recs,
                          int N, float* __restrict__ aggOut) {
    int node = blockIdx.x * 4 + (threadIdx.x >> 6);
    int lane = threadIdx.x & 63;
    if (node >= N) return;
    const float2* xr = (const float2*)x;
    float wn = invs[node];
    float2 xself = xr[(size_t)node * 64 + lane];
    float accx = wn * xself.x, accy = wn * xself.y;
    int e = rowstart[node], e1 = rowstart[node + 1];
    for (; e < e1; ++e) {
        unsigned s = recs[e];
        float w = invs[s];
        float2 v = xr[(size_t)s * 64 + lane];
        accx = fmaf(w, v.x, accx); accy = fmaf(w, v.y, accy);
    }
    float2 o; o.x = accx * wn; o.y = accy * wn;
    ((float2*)aggOut)[(size_t)node * 64 + lane] = o;
}

#define GROWS 32
__global__ __launch_bounds__(128) void k_gemm_f32(float* __restrict__ out, const float* __restrict__ Wm,
                                                  const float* __restrict__ bb,
                                                  const float* __restrict__ x, int N) {
    __shared__ float Ws[64 * DD];
    __shared__ float As[DD * GROWS];
    int t = threadIdx.x;
    int rowBase = blockIdx.x * GROWS;
    {
        int r = t & 31, kq = t >> 5;
        if (rowBase + r < N) {
            const float4* Av = (const float4*)(out + (size_t)(rowBase + r) * DD);
            #pragma unroll
            for (int q = 0; q < 8; q++) {
                float4 v = Av[kq * 8 + q];
                int k = (kq * 8 + q) * 4;
                As[(k + 0) * GROWS + r] = v.x;
                As[(k + 1) * GROWS + r] = v.y;
                As[(k + 2) * GROWS + r] = v.z;
                As[(k + 3) * GROWS + r] = v.w;
            }
        } else {
            #pragma unroll
            for (int q = 0; q < 8; q++) {
                int k = (kq * 8 + q) * 4;
                As[(k + 0) * GROWS + r] = 0.f;
                As[(k + 1) * GROWS + r] = 0.f;
                As[(k + 2) * GROWS + r] = 0.f;
                As[(k + 3) * GROWS + r] = 0.f;
            }
        }
    }
    int tx = t & 15, ty = t >> 4;
    int c0 = tx * 8, r0 = ty * 4;
    float acc[4][8];
    #pragma unroll
    for (int i = 0; i < 4; i++)
        #pragma unroll
        for (int j = 0; j < 8; j++) acc[i][j] = 0.f;
    for (int kk = 0; kk < DD; kk += 64) {
        __syncthreads();
        const float4* Wv = (const float4*)(Wm + (size_t)kk * DD);
        #pragma unroll
        for (int i = 0; i < 16; i++) ((float4*)Ws)[t + i * 128] = Wv[t + i * 128];
        __syncthreads();
        #pragma unroll 4
        for (int k = 0; k < 64; k++) {
            const float4 a = *(const float4*)&As[(kk + k) * GROWS + r0];
            const float4 w0 = *(const float4*)&Ws[k * DD + c0];
            const float4 w1 = *(const float4*)&Ws[k * DD + c0 + 4];
            const float av[4] = {a.x, a.y, a.z, a.w};
            const float wv[8] = {w0.x, w0.y, w0.z, w0.w, w1.x, w1.y, w1.z, w1.w};
            #pragma unroll
            for (int i = 0; i < 4; i++)
                #pragma unroll
                for (int j = 0; j < 8; j++) acc[i][j] = fmaf(av[i], wv[j], acc[i][j]);
        }
    }
    float bv[8];
    {
        float4 b0 = *(const float4*)&bb[c0];
        float4 b1 = *(const float4*)&bb[c0 + 4];
        bv[0] = b0.x; bv[1] = b0.y; bv[2] = b0.z; bv[3] = b0.w;
        bv[4] = b1.x; bv[5] = b1.y; bv[6] = b1.z; bv[7] = b1.w;
    }
    #pragma unroll
    for (int i = 0; i < 4; i++) {
        int row = rowBase + r0 + i;
        if (row < N) {
            const float4 xv0 = *(const float4*)&x[(size_t)row * DD + c0];
            const float4 xv1 = *(const float4*)&x[(size_t)row * DD + c0 + 4];
            float4 o0, o1;
            o0.x = fmaxf(acc[i][0] + bv[0], 0.f) + xv0.x;
            o0.y = fmaxf(acc[i][1] + bv[1], 0.f) + xv0.y;
            o0.z = fmaxf(acc[i][2] + bv[2], 0.f) + xv0.z;
            o0.w = fmaxf(acc[i][3] + bv[3], 0.f) + xv0.w;
            o1.x = fmaxf(acc[i][4] + bv[4], 0.f) + xv1.x;
            o1.y = fmaxf(acc[i][5] + bv[5], 0.f) + xv1.y;
            o1.z = fmaxf(acc[i][6] + bv[6], 0.f) + xv1.z;
            o1.w = fmaxf(acc[i][7] + bv[7], 0.f) + xv1.w;
            *(float4*)&out[(size_t)row * DD + c0] = o0;
            *(float4*)&out[(size_t)row * DD + c0 + 4] = o1;
        }
    }
}

extern "C" void kernel_launch(void* const* d_in, const int* in_sizes, int n_in,
                              void* d_out, int out_size, void* d_ws, size_t ws_size,
                              hipStream_t stream) {
    const float* x = (const float*)d_in[0];
    const float* W = (const float*)d_in[1];
    const float* b = (const float*)d_in[2];
    const int*   ei = (const int*)d_in[3];
    int N = in_sizes[0] / DD;
    int E = in_sizes[3] / 2;
    float* out = (float*)d_out;
    float* outTail = out + (size_t)N * DD;

    int NB = (N + 511) >> BSH;          // buckets of 512 nodes
    int nA = (E + EPB - 1) / EPB;       // A-pass blocks

    // new-path workspace layout
    char* wsb = (char*)d_ws;
    size_t off = 0;
    unsigned* brec = (unsigned*)(wsb + off);  off += (size_t)E * 4;
    unsigned* recs = (unsigned*)(wsb + off);  off += (size_t)E * 4;
    unsigned* xs   = (unsigned*)(wsb + off);  off += (size_t)N * 64 * 4;
    unsigned* aggh = (unsigned*)(wsb + off);  off += (size_t)N * 64 * 4;
    ushort*   Wt   = (ushort*)(wsb + off);    off += (size_t)DD * DD * 2;
    int* H         = (int*)(wsb + off);       off += (size_t)nA * NB * 4;
    int* colsum    = (int*)(wsb + off);       off += (size_t)NB * 4;
    int* rowstart  = (int*)(wsb + off);       off += (size_t)(N + 1) * 4;
    float* invs    = (float*)(wsb + off);     off += (size_t)N * 4;

    bool newpath = (ws_size >= off) && (NB <= 256) && (nA <= 1024) && (N <= 131072) && (E >= 64);

    if (newpath) {
        kA1<<<nA + 64, 256, 0, stream>>>(ei, E, NB, nA, outTail, H, W, Wt);
        k_scanH1<<<NB, 256, 0, stream>>>(H, nA, NB, colsum);
        kA2<<<nA, 256, 0, stream>>>(ei, E, NB, H, colsum, brec);
        kB<<<NB, 256, 0, stream>>>(brec, colsum, NB, N, E, recs, rowstart, invs);
        int n2 = N * 64;
        k_cvt_xs<<<(n2 + 255) / 256, 256, 0, stream>>>((const float2*)x, invs, xs, n2);
        k_agg_s<<<(N + 3) / 4, 256, 0, stream>>>(xs, rowstart, invs, recs, N, aggh);
        k_gemm_mfma<<<(N + 63) / 64, 256, 0, stream>>>((const ushort*)aggh, Wt, b, x, out, N);
    } else {
        // fallback: rank-based build + f32 compute (known good)
        off = 0;
        unsigned* recsF = (unsigned*)(wsb + off);  off += (size_t)E * 4;
        unsigned* rank  = (unsigned*)(wsb + off);  off += (size_t)E * 4;
        int* cnt        = (int*)(wsb + off);       off += (size_t)N * 4;
        int* rowstartF  = (int*)(wsb + off);       off += (size_t)(N + 1) * 4;
        float* invsF    = (float*)(wsb + off);     off += (size_t)N * 4;
        int* bsum       = (int*)(wsb + off);       off += 512 * 4;
        int* boff       = (int*)(wsb + off);       off += 512 * 4;
        int* flagF      = (int*)(wsb + off);

        hipMemsetAsync(cnt, 0, sizeof(int) * (size_t)N, stream);
        k_sniff<<<1, 1024, 0, stream>>>(ei, 1024, flagF);
        k_count_echo<<<(E + 255) / 256, 256, 0, stream>>>(ei, E, cnt, outTail, rank, flagF);
        int nblk = (N + 1023) / 1024;
        k_scan1<<<nblk, 1024, 0, stream>>>(cnt, N, rowstartF, bsum);
        k_scan2<<<1, 128, 0, stream>>>(bsum, nblk, boff);
        k_scan3<<<(N + 255) / 256, 256, 0, stream>>>(N, E, rowstartF, boff, cnt, invsF);
        k_fill_r<<<(E + 255) / 256, 256, 0, stream>>>(ei, E, rowstartF, rank, recsF, flagF);
        k_agg_f32<<<(N + 3) / 4, 256, 0, stream>>>(x, rowstartF, invsF, recsF, N, out);
        k_gemm_f32<<<(N + GROWS - 1) / GROWS, 128, 0, stream>>>(out, W, b, x, N);
    }
}

// Round 12
// 173.298 us; speedup vs baseline: 1.8831x; 1.0587x over previous
//
#include <hip/hip_runtime.h>

// GCNBlock: out0 = relu( (D^-1/2 (A+I) D^-1/2) (x W) + b ) + x   [N,128] f32
//           out1 = edge_index echoed (as float values) appended in d_out
// Round 12: reorder to (Âx)W -> Â(xW): k_gemm_h computes h=bf16(invs*(xW))
// (replaces cvt_xs + gemm_mfma), k_agg_out gathers h and fuses
// relu+bias+residual epilogue. Kills aggh round-trip (51.2MB) + 1 launch.
// CSR build unchanged from round 11 (plain stores — NT stores cost +66us).

#define DD 128
#define EPB 2048      // edges per A-block (8 iters x 256 threads)
#define BSH 9         // bucket shift: 512 nodes per bucket
typedef __attribute__((ext_vector_type(8))) short bf16x8;
typedef __attribute__((ext_vector_type(4))) float f32x4;

__device__ __forceinline__ ushort f2bf(float f) {
    unsigned u = __float_as_uint(f);
    unsigned r = (u + 0x7fffu + ((u >> 16) & 1u)) >> 16;  // RNE
    return (ushort)r;
}
__device__ __forceinline__ float bflo(unsigned u) { return __uint_as_float(u << 16); }
__device__ __forceinline__ float bfhi(unsigned u) { return __uint_as_float(u & 0xffff0000u); }

__device__ __forceinline__ int ld_src(const int* p, int e, int E, int is64) {
    return is64 ? p[2 * e] : p[e];
}
__device__ __forceinline__ int ld_dst(const int* p, int e, int E, int is64) {
    return is64 ? p[2 * (E + e)] : p[E + e];
}

// inline dtype sniff: int64 edge data has all-zero high words.
__device__ __forceinline__ int detect64(const int* __restrict__ p, int E) {
    int lane = threadIdx.x & 63;
    int idx = 2 * lane + 1;
    if (idx >= 2 * E) idx = 2 * E - 1;
    unsigned long long m = __ballot(p[idx] != 0);
    return m == 0ull ? 1 : 0;
}

// ---------- A1: bucket histogram + fused echo (+ tail blocks convert W) ----------
__global__ __launch_bounds__(256) void kA1(const int* __restrict__ ei, int E, int NB, int nA,
                                           float* __restrict__ outTail, int* __restrict__ H,
                                           const float* __restrict__ W, ushort* __restrict__ Wt) {
    int t = threadIdx.x, a = blockIdx.x;
    if (a >= nA) {  // W-conversion tail blocks
        int i = (a - nA) * 256 + t;
        if (i < DD * DD) {
            int c = i >> 7, k = i & 127;
            Wt[i] = f2bf(W[k * DD + c]);
        }
        return;
    }
    __shared__ int hist[256];
    int is64 = detect64(ei, E);
    if (t < NB) hist[t] = 0;
    __syncthreads();
    int base = a * EPB;
    #pragma unroll
    for (int it = 0; it < EPB / 256; ++it) {
        int e = base + it * 256 + t;
        if (e < E) {
            int s = ld_src(ei, e, E, is64);
            int d = ld_dst(ei, e, E, is64);
            outTail[e] = (float)s;
            outTail[E + e] = (float)d;
            atomicAdd(&hist[d >> BSH], 1);
        }
    }
    __syncthreads();
    if (t < NB) H[a * NB + t] = hist[t];
}

// ---------- scanH1: per-column exclusive scan of H (NB blocks, nA<=1024) ----------
__global__ __launch_bounds__(256) void k_scanH1(int* __restrict__ H, int nA, int NB,
                                                int* __restrict__ colsum) {
    __shared__ int s[256];
    int b = blockIdx.x, t = threadIdx.x;
    int K = (nA + 255) / 256;
    int base = t * K;
    int local = 0;
    for (int j = 0; j < K; ++j) {
        int a = base + j;
        if (a < nA) local += H[a * NB + b];
    }
    s[t] = local;
    __syncthreads();
    #pragma unroll
    for (int off = 1; off < 256; off <<= 1) {
        int u = (t >= off) ? s[t - off] : 0;
        __syncthreads();
        s[t] += u;
        __syncthreads();
    }
    int run = s[t] - local;  // exclusive prefix of this thread's chunk
    for (int j = 0; j < K; ++j) {
        int a = base + j;
        if (a < nA) { int v = H[a * NB + b]; H[a * NB + b] = run; run += v; }
    }
    if (t == 255) colsum[b] = s[255];
}

// ---------- A2: scatter packed records; bucketstart derived locally from colsum ----
// record = src | (dst&511)<<17   (needs N <= 131072)
__global__ __launch_bounds__(256) void kA2(const int* __restrict__ ei, int E, int NB,
                                           const int* __restrict__ H,
                                           const int* __restrict__ colsum,
                                           unsigned* __restrict__ brec) {
    __shared__ int bs[256];
    __shared__ int cur[256];
    int t = threadIdx.x, a = blockIdx.x;
    int is64 = detect64(ei, E);
    int v = (t < NB) ? colsum[t] : 0;
    bs[t] = v;
    __syncthreads();
    #pragma unroll
    for (int off = 1; off < 256; off <<= 1) {
        int u = (t >= off) ? bs[t - off] : 0;
        __syncthreads();
        bs[t] += u;
        __syncthreads();
    }
    if (t < NB) cur[t] = H[a * NB + t] + bs[t] - v;  // exclusive bucketstart + block offset
    __syncthreads();
    int base = a * EPB;
    #pragma unroll
    for (int it = 0; it < EPB / 256; ++it) {
        int e = base + it * 256 + t;
        if (e < E) {
            int s = ld_src(ei, e, E, is64);
            int d = ld_dst(ei, e, E, is64);
            int pos = atomicAdd(&cur[d >> BSH], 1);  // LDS atomic
            brec[pos] = (unsigned)s | ((unsigned)(d & 511) << 17);
        }
    }
}

// ---------- B: per-bucket CSR finalize: recs + rowstart + invs ----------
__global__ __launch_bounds__(256) void kB(const unsigned* __restrict__ brec,
                                          const int* __restrict__ colsum, int NB, int N,
                                          int E, unsigned* __restrict__ recs,
                                          int* __restrict__ rowstart, float* __restrict__ invs) {
    __shared__ int bs[256];
    __shared__ int hist[512];
    __shared__ int scan[513];
    __shared__ int cur[512];
    int b = blockIdx.x, t = threadIdx.x;
    int v = (t < NB) ? colsum[t] : 0;
    bs[t] = v;
    __syncthreads();
    #pragma unroll
    for (int off = 1; off < 256; off <<= 1) {
        int u = (t >= off) ? bs[t - off] : 0;
        __syncthreads();
        bs[t] += u;
        __syncthreads();
    }
    if (t < NB) bs[t] -= v;  // exclusive
    hist[t] = 0; hist[t + 256] = 0;
    __syncthreads();
    int lo = bs[b], hi = lo + colsum[b];
    for (int i = lo + t; i < hi; i += 256) atomicAdd(&hist[brec[i] >> 17], 1);
    __syncthreads();
    if (t == 0) {
        int acc = 0;
        for (int j = 0; j < 512; ++j) { scan[j] = acc; acc += hist[j]; }
        scan[512] = acc;
    }
    __syncthreads();
    int nodeBase = b << BSH;
    #pragma unroll
    for (int j = t; j < 512; j += 256) {
        int node = nodeBase + j;
        if (node < N) {
            rowstart[node] = lo + scan[j];
            invs[node] = rsqrtf((float)(1 + hist[j]));  // deg includes self-loop
        }
        cur[j] = lo + scan[j];
    }
    if (b == NB - 1 && t == 0) rowstart[N] = E;
    __syncthreads();
    for (int i = lo + t; i < hi; i += 256) {
        unsigned r = brec[i];
        int pos = atomicAdd(&cur[r >> 17], 1);  // LDS atomic
        recs[pos] = r & 0x1FFFFu;
    }
}

// ---------- k_gemm_h: h = bf16( invs[node] * (x W) )  (swapped-operand MFMA) ----------
// A frag = Wt (W cols), B frag = bf16(x row); D: col=lane&15 -> node,
// row=(lane>>4)*4+reg -> 4 consecutive h cols. Packs 2 bf16/uint into hs.
__global__ __launch_bounds__(256) void k_gemm_h(const float* __restrict__ x,
                                                const ushort* __restrict__ Wt,
                                                const float* __restrict__ invs,
                                                unsigned* __restrict__ hs, int N) {
    int wave = threadIdx.x >> 6, lane = threadIdx.x & 63;
    int rowBase = blockIdx.x * 64 + wave * 16;
    int rfrag = lane & 15, kgrp = lane >> 4;
    f32x4 zero = {0.f, 0.f, 0.f, 0.f};
    f32x4 acc[8];
    #pragma unroll
    for (int n = 0; n < 8; ++n) acc[n] = zero;

    int arow = rowBase + rfrag;
    bool av = arow < N;
    const float* xrow = x + (size_t)(av ? arow : 0) * DD + kgrp * 8;
    const ushort* wbase = Wt + rfrag * DD + kgrp * 8;

    #pragma unroll
    for (int ks = 0; ks < 4; ++ks) {
        bf16x8 bnode = {0, 0, 0, 0, 0, 0, 0, 0};
        if (av) {
            float4 f0 = *(const float4*)(xrow + ks * 32);
            float4 f1 = *(const float4*)(xrow + ks * 32 + 4);
            bnode[0] = (short)f2bf(f0.x); bnode[1] = (short)f2bf(f0.y);
            bnode[2] = (short)f2bf(f0.z); bnode[3] = (short)f2bf(f0.w);
            bnode[4] = (short)f2bf(f1.x); bnode[5] = (short)f2bf(f1.y);
            bnode[6] = (short)f2bf(f1.z); bnode[7] = (short)f2bf(f1.w);
        }
        #pragma unroll
        for (int n = 0; n < 8; ++n) {
            bf16x8 aw = *(const bf16x8*)(wbase + n * 16 * DD + ks * 32);
            acc[n] = __builtin_amdgcn_mfma_f32_16x16x32_bf16(aw, bnode, acc[n], 0, 0, 0);
        }
    }

    int node = rowBase + rfrag;
    if (node < N) {
        float wn = invs[node];
        int csub = kgrp * 4;
        #pragma unroll
        for (int n = 0; n < 8; ++n) {
            int c0 = n * 16 + csub;
            unsigned u0 = (unsigned)f2bf(wn * acc[n][0]) | ((unsigned)f2bf(wn * acc[n][1]) << 16);
            unsigned u1 = (unsigned)f2bf(wn * acc[n][2]) | ((unsigned)f2bf(wn * acc[n][3]) << 16);
            hs[(size_t)node * 64 + (c0 >> 1)] = u0;
            hs[(size_t)node * 64 + (c0 >> 1) + 1] = u1;
        }
    }
}

// ---------- k_agg_out: gather h rows, fused relu+bias+residual epilogue ----------
__global__ void k_agg_out(const unsigned* __restrict__ hs, const int* __restrict__ rowstart,
                          const float* __restrict__ invs, const unsigned* __restrict__ recs,
                          const float* __restrict__ bb, const float* __restrict__ x,
                          float* __restrict__ out, int N) {
    int node = blockIdx.x * 4 + (threadIdx.x >> 6);
    int lane = threadIdx.x & 63;
    if (node >= N) return;
    float wn = invs[node];
    unsigned us = hs[(size_t)node * 64 + lane];  // self: hs[node]*wn = invs^2 * h
    float accx = bflo(us), accy = bfhi(us);
    int e = rowstart[node], e1 = rowstart[node + 1];
    for (; e + 16 <= e1; e += 16) {
        unsigned sv[16], vv[16];
        #pragma unroll
        for (int j = 0; j < 16; ++j) sv[j] = recs[e + j];
        #pragma unroll
        for (int j = 0; j < 16; ++j) vv[j] = hs[(size_t)sv[j] * 64 + lane];
        #pragma unroll
        for (int j = 0; j < 16; ++j) { accx += bflo(vv[j]); accy += bfhi(vv[j]); }
    }
    if (e + 8 <= e1) {
        unsigned sv[8], vv[8];
        #pragma unroll
        for (int j = 0; j < 8; ++j) sv[j] = recs[e + j];
        #pragma unroll
        for (int j = 0; j < 8; ++j) vv[j] = hs[(size_t)sv[j] * 64 + lane];
        #pragma unroll
        for (int j = 0; j < 8; ++j) { accx += bflo(vv[j]); accy += bfhi(vv[j]); }
        e += 8;
    }
    for (; e < e1; ++e) {
        unsigned v0 = hs[(size_t)recs[e] * 64 + lane];
        accx += bflo(v0); accy += bfhi(v0);
    }
    float2 bv = ((const float2*)bb)[lane];
    float2 xv = ((const float2*)x)[(size_t)node * 64 + lane];
    float2 o;
    o.x = fmaxf(accx * wn + bv.x, 0.f) + xv.x;
    o.y = fmaxf(accy * wn + bv.y, 0.f) + xv.y;
    ((float2*)out)[(size_t)node * 64 + lane] = o;
}

// =================== fallback path (shape/ws outside new-path limits) ===================
__global__ void k_sniff(const int* __restrict__ p, int n_check, int* __restrict__ flag) {
    __shared__ int any_nonzero;
    if (threadIdx.x == 0) any_nonzero = 0;
    __syncthreads();
    int j = threadIdx.x;
    if (j < n_check && p[2 * j + 1] != 0) any_nonzero = 1;
    __syncthreads();
    if (threadIdx.x == 0) *flag = any_nonzero ? 0 : 1;
}

__global__ void k_count_echo(const int* __restrict__ ei, int E, int* __restrict__ cnt,
                             float* __restrict__ outTail, unsigned* __restrict__ rank,
                             const int* __restrict__ flagp) {
    int is64 = *flagp;
    int e = blockIdx.x * blockDim.x + threadIdx.x;
    if (e < E) {
        int s = ld_src(ei, e, E, is64);
        int d = ld_dst(ei, e, E, is64);
        outTail[e] = (float)s;
        outTail[E + e] = (float)d;
        rank[e] = (unsigned)atomicAdd(&cnt[d], 1);
    }
}

__global__ void k_scan1(const int* __restrict__ cnt, int N, int* __restrict__ rowstart,
                        int* __restrict__ bsum) {
    __shared__ int s[1024];
    int tid = threadIdx.x;
    int i = blockIdx.x * 1024 + tid;
    int v = (i < N) ? cnt[i] : 0;
    s[tid] = v;
    __syncthreads();
    for (int off = 1; off < 1024; off <<= 1) {
        int t2 = (tid >= off) ? s[tid - off] : 0;
        __syncthreads();
        s[tid] += t2;
        __syncthreads();
    }
    if (i < N) rowstart[i] = s[tid] - v;
    if (tid == 1023) bsum[blockIdx.x] = s[1023];
}

__global__ void k_scan2(const int* __restrict__ bsum, int nblk, int* __restrict__ boff) {
    __shared__ int s[128];
    int t = threadIdx.x;
    if (t < nblk) s[t] = bsum[t];
    __syncthreads();
    if (t == 0) {
        int a = 0;
        for (int i = 0; i < nblk; i++) { int v = s[i]; s[i] = a; a += v; }
    }
    __syncthreads();
    if (t < nblk) boff[t] = s[t];
}

__global__ void k_scan3(int N, int E, int* __restrict__ rowstart, const int* __restrict__ boff,
                        const int* __restrict__ cnt, float* __restrict__ invs) {
    int i = blockIdx.x * blockDim.x + threadIdx.x;
    if (i < N) {
        int r = rowstart[i] + boff[i >> 10];
        rowstart[i] = r;
        invs[i] = rsqrtf((float)(1 + cnt[i]));
    }
    if (i == 0 && blockIdx.x == 0) rowstart[N] = E;
}

__global__ void k_fill_r(const int* __restrict__ ei, int E, const int* __restrict__ rowstart,
                         const unsigned* __restrict__ rank, unsigned* __restrict__ recs,
                         const int* __restrict__ flagp) {
    int is64 = *flagp;
    int e = blockIdx.x * blockDim.x + threadIdx.x;
    if (e < E) {
        int d = ld_dst(ei, e, E, is64);
        int s = ld_src(ei, e, E, is64);
        recs[rowstart[d] + rank[e]] = (unsigned)s;
    }
}

__global__ void k_agg_f32(const float* __restrict__ x, const int* __restrict__ rowstart,
                          const float* __restrict__ invs, const unsigned* __restrict__ recs,
                          int N, float* __restrict__ aggOut) {
    int node = blockIdx.x * 4 + (threadIdx.x >> 6);
    int lane = threadIdx.x & 63;
    if (node >= N) return;
    const float2* xr = (const float2*)x;
    float wn = invs[node];
    float2 xself = xr[(size_t)node * 64 + lane];
    float accx = wn * xself.x, accy = wn * xself.y;
    int e = rowstart[node], e1 = rowstart[node + 1];
    for (; e < e1; ++e) {
        unsigned s = recs[e];
        float w = invs[s];
        float2 v = xr[(size_t)s * 64 + lane];
        accx = fmaf(w, v.x, accx); accy = fmaf(w, v.y, accy);
    }
    float2 o; o.x = accx * wn; o.y = accy * wn;
    ((float2*)aggOut)[(size_t)node * 64 + lane] = o;
}

#define GROWS 32
__global__ __launch_bounds__(128) void k_gemm_f32(float* __restrict__ out, const float* __restrict__ Wm,
                                                  const float* __restrict__ bb,
                                                  const float* __restrict__ x, int N) {
    __shared__ float Ws[64 * DD];
    __shared__ float As[DD * GROWS];
    int t = threadIdx.x;
    int rowBase = blockIdx.x * GROWS;
    {
        int r = t & 31, kq = t >> 5;
        if (rowBase + r < N) {
            const float4* Av = (const float4*)(out + (size_t)(rowBase + r) * DD);
            #pragma unroll
            for (int q = 0; q < 8; q++) {
                float4 v = Av[kq * 8 + q];
                int k = (kq * 8 + q) * 4;
                As[(k + 0) * GROWS + r] = v.x;
                As[(k + 1) * GROWS + r] = v.y;
                As[(k + 2) * GROWS + r] = v.z;
                As[(k + 3) * GROWS + r] = v.w;
            }
        } else {
            #pragma unroll
            for (int q = 0; q < 8; q++) {
                int k = (kq * 8 + q) * 4;
                As[(k + 0) * GROWS + r] = 0.f;
                As[(k + 1) * GROWS + r] = 0.f;
                As[(k + 2) * GROWS + r] = 0.f;
                As[(k + 3) * GROWS + r] = 0.f;
            }
        }
    }
    int tx = t & 15, ty = t >> 4;
    int c0 = tx * 8, r0 = ty * 4;
    float acc[4][8];
    #pragma unroll
    for (int i = 0; i < 4; i++)
        #pragma unroll
        for (int j = 0; j < 8; j++) acc[i][j] = 0.f;
    for (int kk = 0; kk < DD; kk += 64) {
        __syncthreads();
        const float4* Wv = (const float4*)(Wm + (size_t)kk * DD);
        #pragma unroll
        for (int i = 0; i < 16; i++) ((float4*)Ws)[t + i * 128] = Wv[t + i * 128];
        __syncthreads();
        #pragma unroll 4
        for (int k = 0; k < 64; k++) {
            const float4 a = *(const float4*)&As[(kk + k) * GROWS + r0];
            const float4 w0 = *(const float4*)&Ws[k * DD + c0];
            const float4 w1 = *(const float4*)&Ws[k * DD + c0 + 4];
            const float av[4] = {a.x, a.y, a.z, a.w};
            const float wv[8] = {w0.x, w0.y, w0.z, w0.w, w1.x, w1.y, w1.z, w1.w};
            #pragma unroll
            for (int i = 0; i < 4; i++)
                #pragma unroll
                for (int j = 0; j < 8; j++) acc[i][j] = fmaf(av[i], wv[j], acc[i][j]);
        }
    }
    float bv[8];
    {
        float4 b0 = *(const float4*)&bb[c0];
        float4 b1 = *(const float4*)&bb[c0 + 4];
        bv[0] = b0.x; bv[1] = b0.y; bv[2] = b0.z; bv[3] = b0.w;
        bv[4] = b1.x; bv[5] = b1.y; bv[6] = b1.z; bv[7] = b1.w;
    }
    #pragma unroll
    for (int i = 0; i < 4; i++) {
        int row = rowBase + r0 + i;
        if (row < N) {
            const float4 xv0 = *(const float4*)&x[(size_t)row * DD + c0];
            const float4 xv1 = *(const float4*)&x[(size_t)row * DD + c0 + 4];
            float4 o0, o1;
            o0.x = fmaxf(acc[i][0] + bv[0], 0.f) + xv0.x;
            o0.y = fmaxf(acc[i][1] + bv[1], 0.f) + xv0.y;
            o0.z = fmaxf(acc[i][2] + bv[2], 0.f) + xv0.z;
            o0.w = fmaxf(acc[i][3] + bv[3], 0.f) + xv0.w;
            o1.x = fmaxf(acc[i][4] + bv[4], 0.f) + xv1.x;
            o1.y = fmaxf(acc[i][5] + bv[5], 0.f) + xv1.y;
            o1.z = fmaxf(acc[i][6] + bv[6], 0.f) + xv1.z;
            o1.w = fmaxf(acc[i][7] + bv[7], 0.f) + xv1.w;
            *(float4*)&out[(size_t)row * DD + c0] = o0;
            *(float4*)&out[(size_t)row * DD + c0 + 4] = o1;
        }
    }
}

extern "C" void kernel_launch(void* const* d_in, const int* in_sizes, int n_in,
                              void* d_out, int out_size, void* d_ws, size_t ws_size,
                              hipStream_t stream) {
    const float* x = (const float*)d_in[0];
    const float* W = (const float*)d_in[1];
    const float* b = (const float*)d_in[2];
    const int*   ei = (const int*)d_in[3];
    int N = in_sizes[0] / DD;
    int E = in_sizes[3] / 2;
    float* out = (float*)d_out;
    float* outTail = out + (size_t)N * DD;

    int NB = (N + 511) >> BSH;          // buckets of 512 nodes
    int nA = (E + EPB - 1) / EPB;       // A-pass blocks

    // new-path workspace layout
    char* wsb = (char*)d_ws;
    size_t off = 0;
    unsigned* brec = (unsigned*)(wsb + off);  off += (size_t)E * 4;
    unsigned* recs = (unsigned*)(wsb + off);  off += (size_t)E * 4;
    unsigned* hs   = (unsigned*)(wsb + off);  off += (size_t)N * 64 * 4;
    ushort*   Wt   = (ushort*)(wsb + off);    off += (size_t)DD * DD * 2;
    int* H         = (int*)(wsb + off);       off += (size_t)nA * NB * 4;
    int* colsum    = (int*)(wsb + off);       off += (size_t)NB * 4;
    int* rowstart  = (int*)(wsb + off);       off += (size_t)(N + 1) * 4;
    float* invs    = (float*)(wsb + off);     off += (size_t)N * 4;

    bool newpath = (ws_size >= off) && (NB <= 256) && (nA <= 1024) && (N <= 131072) && (E >= 64);

    if (newpath) {
        kA1<<<nA + 64, 256, 0, stream>>>(ei, E, NB, nA, outTail, H, W, Wt);
        k_scanH1<<<NB, 256, 0, stream>>>(H, nA, NB, colsum);
        kA2<<<nA, 256, 0, stream>>>(ei, E, NB, H, colsum, brec);
        kB<<<NB, 256, 0, stream>>>(brec, colsum, NB, N, E, recs, rowstart, invs);
        k_gemm_h<<<(N + 63) / 64, 256, 0, stream>>>(x, Wt, invs, hs, N);
        k_agg_out<<<(N + 3) / 4, 256, 0, stream>>>(hs, rowstart, invs, recs, b, x, out, N);
    } else {
        // fallback: rank-based build + f32 compute (known good)
        off = 0;
        unsigned* recsF = (unsigned*)(wsb + off);  off += (size_t)E * 4;
        unsigned* rank  = (unsigned*)(wsb + off);  off += (size_t)E * 4;
        int* cnt        = (int*)(wsb + off);       off += (size_t)N * 4;
        int* rowstartF  = (int*)(wsb + off);       off += (size_t)(N + 1) * 4;
        float* invsF    = (float*)(wsb + off);     off += (size_t)N * 4;
        int* bsum       = (int*)(wsb + off);       off += 512 * 4;
        int* boff       = (int*)(wsb + off);       off += 512 * 4;
        int* flagF      = (int*)(wsb + off);

        hipMemsetAsync(cnt, 0, sizeof(int) * (size_t)N, stream);
        k_sniff<<<1, 1024, 0, stream>>>(ei, 1024, flagF);
        k_count_echo<<<(E + 255) / 256, 256, 0, stream>>>(ei, E, cnt, outTail, rank, flagF);
        int nblk = (N + 1023) / 1024;
        k_scan1<<<nblk, 1024, 0, stream>>>(cnt, N, rowstartF, bsum);
        k_scan2<<<1, 128, 0, stream>>>(bsum, nblk, boff);
        k_scan3<<<(N + 255) / 256, 256, 0, stream>>>(N, E, rowstartF, boff, cnt, invsF);
        k_fill_r<<<(E + 255) / 256, 256, 0, stream>>>(ei, E, rowstartF, rank, recsF, flagF);
        k_agg_f32<<<(N + 3) / 4, 256, 0, stream>>>(x, rowstartF, invsF, recsF, N, out);
        k_gemm_f32<<<(N + GROWS - 1) / GROWS, 128, 0, stream>>>(out, W, b, x, N);
    }
}

// Round 13
// 163.824 us; speedup vs baseline: 1.9920x; 1.0578x over previous
//
#include <hip/hip_runtime.h>

// GCNBlock: out0 = relu( (D^-1/2 (A+I) D^-1/2) (x W) + b ) + x   [N,128] f32
//           out1 = edge_index echoed (as float values) appended in d_out
// Round 13: build-kernel latency fixes. kB: 256->512 threads + parallel
// 512-wide scan (was t==0 serial loop, 196 blocks @ 0.77 waves/SIMD).
// gemm_h: uint2-packed hs stores. Compute path unchanged (agg at roofline).

#define DD 128
#define EPB 2048      // edges per A-block (8 iters x 256 threads)
#define BSH 9         // bucket shift: 512 nodes per bucket
typedef __attribute__((ext_vector_type(8))) short bf16x8;
typedef __attribute__((ext_vector_type(4))) float f32x4;

__device__ __forceinline__ ushort f2bf(float f) {
    unsigned u = __float_as_uint(f);
    unsigned r = (u + 0x7fffu + ((u >> 16) & 1u)) >> 16;  // RNE
    return (ushort)r;
}
__device__ __forceinline__ float bflo(unsigned u) { return __uint_as_float(u << 16); }
__device__ __forceinline__ float bfhi(unsigned u) { return __uint_as_float(u & 0xffff0000u); }

__device__ __forceinline__ int ld_src(const int* p, int e, int E, int is64) {
    return is64 ? p[2 * e] : p[e];
}
__device__ __forceinline__ int ld_dst(const int* p, int e, int E, int is64) {
    return is64 ? p[2 * (E + e)] : p[E + e];
}

// inline dtype sniff: int64 edge data has all-zero high words.
__device__ __forceinline__ int detect64(const int* __restrict__ p, int E) {
    int lane = threadIdx.x & 63;
    int idx = 2 * lane + 1;
    if (idx >= 2 * E) idx = 2 * E - 1;
    unsigned long long m = __ballot(p[idx] != 0);
    return m == 0ull ? 1 : 0;
}

// ---------- A1: bucket histogram + fused echo (+ tail blocks convert W) ----------
__global__ __launch_bounds__(256) void kA1(const int* __restrict__ ei, int E, int NB, int nA,
                                           float* __restrict__ outTail, int* __restrict__ H,
                                           const float* __restrict__ W, ushort* __restrict__ Wt) {
    int t = threadIdx.x, a = blockIdx.x;
    if (a >= nA) {  // W-conversion tail blocks
        int i = (a - nA) * 256 + t;
        if (i < DD * DD) {
            int c = i >> 7, k = i & 127;
            Wt[i] = f2bf(W[k * DD + c]);
        }
        return;
    }
    __shared__ int hist[256];
    int is64 = detect64(ei, E);
    if (t < NB) hist[t] = 0;
    __syncthreads();
    int base = a * EPB;
    #pragma unroll
    for (int it = 0; it < EPB / 256; ++it) {
        int e = base + it * 256 + t;
        if (e < E) {
            int s = ld_src(ei, e, E, is64);
            int d = ld_dst(ei, e, E, is64);
            outTail[e] = (float)s;
            outTail[E + e] = (float)d;
            atomicAdd(&hist[d >> BSH], 1);
        }
    }
    __syncthreads();
    if (t < NB) H[a * NB + t] = hist[t];
}

// ---------- scanH1: per-column exclusive scan of H (NB blocks, nA<=1024) ----------
__global__ __launch_bounds__(256) void k_scanH1(int* __restrict__ H, int nA, int NB,
                                                int* __restrict__ colsum) {
    __shared__ int s[256];
    int b = blockIdx.x, t = threadIdx.x;
    int K = (nA + 255) / 256;
    int base = t * K;
    int local = 0;
    for (int j = 0; j < K; ++j) {
        int a = base + j;
        if (a < nA) local += H[a * NB + b];
    }
    s[t] = local;
    __syncthreads();
    #pragma unroll
    for (int off = 1; off < 256; off <<= 1) {
        int u = (t >= off) ? s[t - off] : 0;
        __syncthreads();
        s[t] += u;
        __syncthreads();
    }
    int run = s[t] - local;  // exclusive prefix of this thread's chunk
    for (int j = 0; j < K; ++j) {
        int a = base + j;
        if (a < nA) { int v = H[a * NB + b]; H[a * NB + b] = run; run += v; }
    }
    if (t == 255) colsum[b] = s[255];
}

// ---------- A2: scatter packed records; bucketstart derived locally from colsum ----
// record = src | (dst&511)<<17   (needs N <= 131072)
__global__ __launch_bounds__(256) void kA2(const int* __restrict__ ei, int E, int NB,
                                           const int* __restrict__ H,
                                           const int* __restrict__ colsum,
                                           unsigned* __restrict__ brec) {
    __shared__ int bs[256];
    __shared__ int cur[256];
    int t = threadIdx.x, a = blockIdx.x;
    int is64 = detect64(ei, E);
    int v = (t < NB) ? colsum[t] : 0;
    bs[t] = v;
    __syncthreads();
    #pragma unroll
    for (int off = 1; off < 256; off <<= 1) {
        int u = (t >= off) ? bs[t - off] : 0;
        __syncthreads();
        bs[t] += u;
        __syncthreads();
    }
    if (t < NB) cur[t] = H[a * NB + t] + bs[t] - v;  // exclusive bucketstart + block offset
    __syncthreads();
    int base = a * EPB;
    #pragma unroll
    for (int it = 0; it < EPB / 256; ++it) {
        int e = base + it * 256 + t;
        if (e < E) {
            int s = ld_src(ei, e, E, is64);
            int d = ld_dst(ei, e, E, is64);
            int pos = atomicAdd(&cur[d >> BSH], 1);  // LDS atomic
            brec[pos] = (unsigned)s | ((unsigned)(d & 511) << 17);
        }
    }
}

// ---------- B: per-bucket CSR finalize (512 threads, parallel scans) ----------
__global__ __launch_bounds__(512) void kB(const unsigned* __restrict__ brec,
                                          const int* __restrict__ colsum, int NB, int N,
                                          int E, unsigned* __restrict__ recs,
                                          int* __restrict__ rowstart, float* __restrict__ invs) {
    __shared__ int bs[256];
    __shared__ int hist[512];
    __shared__ int scn[512];
    __shared__ int cur[512];
    int b = blockIdx.x, t = threadIdx.x;
    // bucketstart: inclusive scan of colsum on first 256 threads
    if (t < 256) bs[t] = (t < NB) ? colsum[t] : 0;
    __syncthreads();
    #pragma unroll
    for (int off = 1; off < 256; off <<= 1) {
        int u = 0;
        if (t < 256 && t >= off) u = bs[t - off];
        __syncthreads();
        if (t < 256) bs[t] += u;
        __syncthreads();
    }
    int cs = colsum[b];
    int hi = bs[b];          // inclusive
    int lo = hi - cs;        // exclusive
    hist[t] = 0;
    __syncthreads();
    for (int i = lo + t; i < hi; i += 512) atomicAdd(&hist[brec[i] >> 17], 1);
    __syncthreads();
    int hv = hist[t];
    scn[t] = hv;
    __syncthreads();
    #pragma unroll
    for (int off = 1; off < 512; off <<= 1) {
        int u = (t >= off) ? scn[t - off] : 0;
        __syncthreads();
        scn[t] += u;
        __syncthreads();
    }
    int excl = scn[t] - hv;
    int node = (b << BSH) + t;
    if (node < N) {
        rowstart[node] = lo + excl;
        invs[node] = rsqrtf((float)(1 + hv));  // deg includes self-loop
    }
    cur[t] = lo + excl;
    if (b == NB - 1 && t == 0) rowstart[N] = E;
    __syncthreads();
    for (int i = lo + t; i < hi; i += 512) {
        unsigned r = brec[i];
        int pos = atomicAdd(&cur[r >> 17], 1);  // LDS atomic
        recs[pos] = r & 0x1FFFFu;
    }
}

// ---------- k_gemm_h: h = bf16( invs[node] * (x W) )  (swapped-operand MFMA) ----------
__global__ __launch_bounds__(256) void k_gemm_h(const float* __restrict__ x,
                                                const ushort* __restrict__ Wt,
                                                const float* __restrict__ invs,
                                                unsigned* __restrict__ hs, int N) {
    int wave = threadIdx.x >> 6, lane = threadIdx.x & 63;
    int rowBase = blockIdx.x * 64 + wave * 16;
    int rfrag = lane & 15, kgrp = lane >> 4;
    f32x4 zero = {0.f, 0.f, 0.f, 0.f};
    f32x4 acc[8];
    #pragma unroll
    for (int n = 0; n < 8; ++n) acc[n] = zero;

    int arow = rowBase + rfrag;
    bool av = arow < N;
    const float* xrow = x + (size_t)(av ? arow : 0) * DD + kgrp * 8;
    const ushort* wbase = Wt + rfrag * DD + kgrp * 8;

    #pragma unroll
    for (int ks = 0; ks < 4; ++ks) {
        bf16x8 bnode = {0, 0, 0, 0, 0, 0, 0, 0};
        if (av) {
            float4 f0 = *(const float4*)(xrow + ks * 32);
            float4 f1 = *(const float4*)(xrow + ks * 32 + 4);
            bnode[0] = (short)f2bf(f0.x); bnode[1] = (short)f2bf(f0.y);
            bnode[2] = (short)f2bf(f0.z); bnode[3] = (short)f2bf(f0.w);
            bnode[4] = (short)f2bf(f1.x); bnode[5] = (short)f2bf(f1.y);
            bnode[6] = (short)f2bf(f1.z); bnode[7] = (short)f2bf(f1.w);
        }
        #pragma unroll
        for (int n = 0; n < 8; ++n) {
            bf16x8 aw = *(const bf16x8*)(wbase + n * 16 * DD + ks * 32);
            acc[n] = __builtin_amdgcn_mfma_f32_16x16x32_bf16(aw, bnode, acc[n], 0, 0, 0);
        }
    }

    int node = rowBase + rfrag;
    if (node < N) {
        float wn = invs[node];
        int csub = kgrp * 4;
        #pragma unroll
        for (int n = 0; n < 8; ++n) {
            int c0 = n * 16 + csub;
            uint2 u;
            u.x = (unsigned)f2bf(wn * acc[n][0]) | ((unsigned)f2bf(wn * acc[n][1]) << 16);
            u.y = (unsigned)f2bf(wn * acc[n][2]) | ((unsigned)f2bf(wn * acc[n][3]) << 16);
            *(uint2*)&hs[(size_t)node * 64 + (c0 >> 1)] = u;
        }
    }
}

// ---------- k_agg_out: gather h rows, fused relu+bias+residual epilogue ----------
__global__ void k_agg_out(const unsigned* __restrict__ hs, const int* __restrict__ rowstart,
                          const float* __restrict__ invs, const unsigned* __restrict__ recs,
                          const float* __restrict__ bb, const float* __restrict__ x,
                          float* __restrict__ out, int N) {
    int node = blockIdx.x * 4 + (threadIdx.x >> 6);
    int lane = threadIdx.x & 63;
    if (node >= N) return;
    float wn = invs[node];
    unsigned us = hs[(size_t)node * 64 + lane];  // self: hs[node]*wn = invs^2 * h
    float accx = bflo(us), accy = bfhi(us);
    int e = rowstart[node], e1 = rowstart[node + 1];
    for (; e + 16 <= e1; e += 16) {
        unsigned sv[16], vv[16];
        #pragma unroll
        for (int j = 0; j < 16; ++j) sv[j] = recs[e + j];
        #pragma unroll
        for (int j = 0; j < 16; ++j) vv[j] = hs[(size_t)sv[j] * 64 + lane];
        #pragma unroll
        for (int j = 0; j < 16; ++j) { accx += bflo(vv[j]); accy += bfhi(vv[j]); }
    }
    if (e + 8 <= e1) {
        unsigned sv[8], vv[8];
        #pragma unroll
        for (int j = 0; j < 8; ++j) sv[j] = recs[e + j];
        #pragma unroll
        for (int j = 0; j < 8; ++j) vv[j] = hs[(size_t)sv[j] * 64 + lane];
        #pragma unroll
        for (int j = 0; j < 8; ++j) { accx += bflo(vv[j]); accy += bfhi(vv[j]); }
        e += 8;
    }
    for (; e < e1; ++e) {
        unsigned v0 = hs[(size_t)recs[e] * 64 + lane];
        accx += bflo(v0); accy += bfhi(v0);
    }
    float2 bv = ((const float2*)bb)[lane];
    float2 xv = ((const float2*)x)[(size_t)node * 64 + lane];
    float2 o;
    o.x = fmaxf(accx * wn + bv.x, 0.f) + xv.x;
    o.y = fmaxf(accy * wn + bv.y, 0.f) + xv.y;
    ((float2*)out)[(size_t)node * 64 + lane] = o;
}

// =================== fallback path (shape/ws outside new-path limits) ===================
__global__ void k_sniff(const int* __restrict__ p, int n_check, int* __restrict__ flag) {
    __shared__ int any_nonzero;
    if (threadIdx.x == 0) any_nonzero = 0;
    __syncthreads();
    int j = threadIdx.x;
    if (j < n_check && p[2 * j + 1] != 0) any_nonzero = 1;
    __syncthreads();
    if (threadIdx.x == 0) *flag = any_nonzero ? 0 : 1;
}

__global__ void k_count_echo(const int* __restrict__ ei, int E, int* __restrict__ cnt,
                             float* __restrict__ outTail, unsigned* __restrict__ rank,
                             const int* __restrict__ flagp) {
    int is64 = *flagp;
    int e = blockIdx.x * blockDim.x + threadIdx.x;
    if (e < E) {
        int s = ld_src(ei, e, E, is64);
        int d = ld_dst(ei, e, E, is64);
        outTail[e] = (float)s;
        outTail[E + e] = (float)d;
        rank[e] = (unsigned)atomicAdd(&cnt[d], 1);
    }
}

__global__ void k_scan1(const int* __restrict__ cnt, int N, int* __restrict__ rowstart,
                        int* __restrict__ bsum) {
    __shared__ int s[1024];
    int tid = threadIdx.x;
    int i = blockIdx.x * 1024 + tid;
    int v = (i < N) ? cnt[i] : 0;
    s[tid] = v;
    __syncthreads();
    for (int off = 1; off < 1024; off <<= 1) {
        int t2 = (tid >= off) ? s[tid - off] : 0;
        __syncthreads();
        s[tid] += t2;
        __syncthreads();
    }
    if (i < N) rowstart[i] = s[tid] - v;
    if (tid == 1023) bsum[blockIdx.x] = s[1023];
}

__global__ void k_scan2(const int* __restrict__ bsum, int nblk, int* __restrict__ boff) {
    __shared__ int s[128];
    int t = threadIdx.x;
    if (t < nblk) s[t] = bsum[t];
    __syncthreads();
    if (t == 0) {
        int a = 0;
        for (int i = 0; i < nblk; i++) { int v = s[i]; s[i] = a; a += v; }
    }
    __syncthreads();
    if (t < nblk) boff[t] = s[t];
}

__global__ void k_scan3(int N, int E, int* __restrict__ rowstart, const int* __restrict__ boff,
                        const int* __restrict__ cnt, float* __restrict__ invs) {
    int i = blockIdx.x * blockDim.x + threadIdx.x;
    if (i < N) {
        int r = rowstart[i] + boff[i >> 10];
        rowstart[i] = r;
        invs[i] = rsqrtf((float)(1 + cnt[i]));
    }
    if (i == 0 && blockIdx.x == 0) rowstart[N] = E;
}

__global__ void k_fill_r(const int* __restrict__ ei, int E, const int* __restrict__ rowstart,
                         const unsigned* __restrict__ rank, unsigned* __restrict__ recs,
                         const int* __restrict__ flagp) {
    int is64 = *flagp;
    int e = blockIdx.x * blockDim.x + threadIdx.x;
    if (e < E) {
        int d = ld_dst(ei, e, E, is64);
        int s = ld_src(ei, e, E, is64);
        recs[rowstart[d] + rank[e]] = (unsigned)s;
    }
}

__global__ void k_agg_f32(const float* __restrict__ x, const int* __restrict__ rowstart,
                          const float* __restrict__ invs, const unsigned* __restrict__ recs,
                          int N, float* __restrict__ aggOut) {
    int node = blockIdx.x * 4 + (threadIdx.x >> 6);
    int lane = threadIdx.x & 63;
    if (node >= N) return;
    const float2* xr = (const float2*)x;
    float wn = invs[node];
    float2 xself = xr[(size_t)node * 64 + lane];
    float accx = wn * xself.x, accy = wn * xself.y;
    int e = rowstart[node], e1 = rowstart[node + 1];
    for (; e < e1; ++e) {
        unsigned s = recs[e];
        float w = invs[s];
        float2 v = xr[(size_t)s * 64 + lane];
        accx = fmaf(w, v.x, accx); accy = fmaf(w, v.y, accy);
    }
    float2 o; o.x = accx * wn; o.y = accy * wn;
    ((float2*)aggOut)[(size_t)node * 64 + lane] = o;
}

#define GROWS 32
__global__ __launch_bounds__(128) void k_gemm_f32(float* __restrict__ out, const float* __restrict__ Wm,
                                                  const float* __restrict__ bb,
                                                  const float* __restrict__ x, int N) {
    __shared__ float Ws[64 * DD];
    __shared__ float As[DD * GROWS];
    int t = threadIdx.x;
    int rowBase = blockIdx.x * GROWS;
    {
        int r = t & 31, kq = t >> 5;
        if (rowBase + r < N) {
            const float4* Av = (const float4*)(out + (size_t)(rowBase + r) * DD);
            #pragma unroll
            for (int q = 0; q < 8; q++) {
                float4 v = Av[kq * 8 + q];
                int k = (kq * 8 + q) * 4;
                As[(k + 0) * GROWS + r] = v.x;
                As[(k + 1) * GROWS + r] = v.y;
                As[(k + 2) * GROWS + r] = v.z;
                As[(k + 3) * GROWS + r] = v.w;
            }
        } else {
            #pragma unroll
            for (int q = 0; q < 8; q++) {
                int k = (kq * 8 + q) * 4;
                As[(k + 0) * GROWS + r] = 0.f;
                As[(k + 1) * GROWS + r] = 0.f;
                As[(k + 2) * GROWS + r] = 0.f;
                As[(k + 3) * GROWS + r] = 0.f;
            }
        }
    }
    int tx = t & 15, ty = t >> 4;
    int c0 = tx * 8, r0 = ty * 4;
    float acc[4][8];
    #pragma unroll
    for (int i = 0; i < 4; i++)
        #pragma unroll
        for (int j = 0; j < 8; j++) acc[i][j] = 0.f;
    for (int kk = 0; kk < DD; kk += 64) {
        __syncthreads();
        const float4* Wv = (const float4*)(Wm + (size_t)kk * DD);
        #pragma unroll
        for (int i = 0; i < 16; i++) ((float4*)Ws)[t + i * 128] = Wv[t + i * 128];
        __syncthreads();
        #pragma unroll 4
        for (int k = 0; k < 64; k++) {
            const float4 a = *(const float4*)&As[(kk + k) * GROWS + r0];
            const float4 w0 = *(const float4*)&Ws[k * DD + c0];
            const float4 w1 = *(const float4*)&Ws[k * DD + c0 + 4];
            const float av[4] = {a.x, a.y, a.z, a.w};
            const float wv[8] = {w0.x, w0.y, w0.z, w0.w, w1.x, w1.y, w1.z, w1.w};
            #pragma unroll
            for (int i = 0; i < 4; i++)
                #pragma unroll
                for (int j = 0; j < 8; j++) acc[i][j] = fmaf(av[i], wv[j], acc[i][j]);
        }
    }
    float bv[8];
    {
        float4 b0 = *(const float4*)&bb[c0];
        float4 b1 = *(const float4*)&bb[c0 + 4];
        bv[0] = b0.x; bv[1] = b0.y; bv[2] = b0.z; bv[3] = b0.w;
        bv[4] = b1.x; bv[5] = b1.y; bv[6] = b1.z; bv[7] = b1.w;
    }
    #pragma unroll
    for (int i = 0; i < 4; i++) {
        int row = rowBase + r0 + i;
        if (row < N) {
            const float4 xv0 = *(const float4*)&x[(size_t)row * DD + c0];
            const float4 xv1 = *(const float4*)&x[(size_t)row * DD + c0 + 4];
            float4 o0, o1;
            o0.x = fmaxf(acc[i][0] + bv[0], 0.f) + xv0.x;
            o0.y = fmaxf(acc[i][1] + bv[1], 0.f) + xv0.y;
            o0.z = fmaxf(acc[i][2] + bv[2], 0.f) + xv0.z;
            o0.w = fmaxf(acc[i][3] + bv[3], 0.f) + xv0.w;
            o1.x = fmaxf(acc[i][4] + bv[4], 0.f) + xv1.x;
            o1.y = fmaxf(acc[i][5] + bv[5], 0.f) + xv1.y;
            o1.z = fmaxf(acc[i][6] + bv[6], 0.f) + xv1.z;
            o1.w = fmaxf(acc[i][7] + bv[7], 0.f) + xv1.w;
            *(float4*)&out[(size_t)row * DD + c0] = o0;
            *(float4*)&out[(size_t)row * DD + c0 + 4] = o1;
        }
    }
}

extern "C" void kernel_launch(void* const* d_in, const int* in_sizes, int n_in,
                              void* d_out, int out_size, void* d_ws, size_t ws_size,
                              hipStream_t stream) {
    const float* x = (const float*)d_in[0];
    const float* W = (const float*)d_in[1];
    const float* b = (const float*)d_in[2];
    const int*   ei = (const int*)d_in[3];
    int N = in_sizes[0] / DD;
    int E = in_sizes[3] / 2;
    float* out = (float*)d_out;
    float* outTail = out + (size_t)N * DD;

    int NB = (N + 511) >> BSH;          // buckets of 512 nodes
    int nA = (E + EPB - 1) / EPB;       // A-pass blocks

    // new-path workspace layout
    char* wsb = (char*)d_ws;
    size_t off = 0;
    unsigned* brec = (unsigned*)(wsb + off);  off += (size_t)E * 4;
    unsigned* recs = (unsigned*)(wsb + off);  off += (size_t)E * 4;
    unsigned* hs   = (unsigned*)(wsb + off);  off += (size_t)N * 64 * 4;
    ushort*   Wt   = (ushort*)(wsb + off);    off += (size_t)DD * DD * 2;
    int* H         = (int*)(wsb + off);       off += (size_t)nA * NB * 4;
    int* colsum    = (int*)(wsb + off);       off += (size_t)NB * 4;
    int* rowstart  = (int*)(wsb + off);       off += (size_t)(N + 1) * 4;
    float* invs    = (float*)(wsb + off);     off += (size_t)N * 4;

    bool newpath = (ws_size >= off) && (NB <= 256) && (nA <= 1024) && (N <= 131072) && (E >= 64);

    if (newpath) {
        kA1<<<nA + 64, 256, 0, stream>>>(ei, E, NB, nA, outTail, H, W, Wt);
        k_scanH1<<<NB, 256, 0, stream>>>(H, nA, NB, colsum);
        kA2<<<nA, 256, 0, stream>>>(ei, E, NB, H, colsum, brec);
        kB<<<NB, 512, 0, stream>>>(brec, colsum, NB, N, E, recs, rowstart, invs);
        k_gemm_h<<<(N + 63) / 64, 256, 0, stream>>>(x, Wt, invs, hs, N);
        k_agg_out<<<(N + 3) / 4, 256, 0, stream>>>(hs, rowstart, invs, recs, b, x, out, N);
    } else {
        // fallback: rank-based build + f32 compute (known good)
        off = 0;
        unsigned* recsF = (unsigned*)(wsb + off);  off += (size_t)E * 4;
        unsigned* rank  = (unsigned*)(wsb + off);  off += (size_t)E * 4;
        int* cnt        = (int*)(wsb + off);       off += (size_t)N * 4;
        int* rowstartF  = (int*)(wsb + off);       off += (size_t)(N + 1) * 4;
        float* invsF    = (float*)(wsb + off);     off += (size_t)N * 4;
        int* bsum       = (int*)(wsb + off);       off += 512 * 4;
        int* boff       = (int*)(wsb + off);       off += 512 * 4;
        int* flagF      = (int*)(wsb + off);

        hipMemsetAsync(cnt, 0, sizeof(int) * (size_t)N, stream);
        k_sniff<<<1, 1024, 0, stream>>>(ei, 1024, flagF);
        k_count_echo<<<(E + 255) / 256, 256, 0, stream>>>(ei, E, cnt, outTail, rank, flagF);
        int nblk = (N + 1023) / 1024;
        k_scan1<<<nblk, 1024, 0, stream>>>(cnt, N, rowstartF, bsum);
        k_scan2<<<1, 128, 0, stream>>>(bsum, nblk, boff);
        k_scan3<<<(N + 255) / 256, 256, 0, stream>>>(N, E, rowstartF, boff, cnt, invsF);
        k_fill_r<<<(E + 255) / 256, 256, 0, stream>>>(ei, E, rowstartF, rank, recsF, flagF);
        k_agg_f32<<<(N + 3) / 4, 256, 0, stream>>>(x, rowstartF, invsF, recsF, N, out);
        k_gemm_f32<<<(N + GROWS - 1) / GROWS, 128, 0, stream>>>(out, W, b, x, N);
    }
}

// Round 14
// 153.422 us; speedup vs baseline: 2.1270x; 1.0678x over previous
//
#include <hip/hip_runtime.h>

// GCNBlock: out0 = relu( (D^-1/2 (A+I) D^-1/2) (x W) + b ) + x   [N,128] f32
//           out1 = edge_index echoed (as float values) appended in d_out
// Round 14: fp8(e4m3) gather payload — h stored as fp8 (128B/row = 1 cache
// line), f32 accumulate. Halves gather traffic (agg_out was 79.5us, half the
// total). Degree-normalized sums keep quant error ~0.01 rms regardless of deg.
// Compile-time fallback to bf16 payload if cvt builtins unavailable.

#define DD 128
#define EPB 2048      // edges per A-block (8 iters x 256 threads)
#define BSH 9         // bucket shift: 512 nodes per bucket
typedef __attribute__((ext_vector_type(8))) short bf16x8;
typedef __attribute__((ext_vector_type(4))) float f32x4;
typedef __attribute__((ext_vector_type(2))) float f32x2;

#if __has_builtin(__builtin_amdgcn_cvt_pk_fp8_f32) && __has_builtin(__builtin_amdgcn_cvt_pk_f32_fp8)
#define FP8PATH 1
#else
#define FP8PATH 0
#endif

__device__ __forceinline__ ushort f2bf(float f) {
    unsigned u = __float_as_uint(f);
    unsigned r = (u + 0x7fffu + ((u >> 16) & 1u)) >> 16;  // RNE
    return (ushort)r;
}
__device__ __forceinline__ float bflo(unsigned u) { return __uint_as_float(u << 16); }
__device__ __forceinline__ float bfhi(unsigned u) { return __uint_as_float(u & 0xffff0000u); }

__device__ __forceinline__ int ld_src(const int* p, int e, int E, int is64) {
    return is64 ? p[2 * e] : p[e];
}
__device__ __forceinline__ int ld_dst(const int* p, int e, int E, int is64) {
    return is64 ? p[2 * (E + e)] : p[E + e];
}

// inline dtype sniff: int64 edge data has all-zero high words.
__device__ __forceinline__ int detect64(const int* __restrict__ p, int E) {
    int lane = threadIdx.x & 63;
    int idx = 2 * lane + 1;
    if (idx >= 2 * E) idx = 2 * E - 1;
    unsigned long long m = __ballot(p[idx] != 0);
    return m == 0ull ? 1 : 0;
}

// ---------- A1: bucket histogram + fused echo (+ tail blocks convert W) ----------
__global__ __launch_bounds__(256) void kA1(const int* __restrict__ ei, int E, int NB, int nA,
                                           float* __restrict__ outTail, int* __restrict__ H,
                                           const float* __restrict__ W, ushort* __restrict__ Wt) {
    int t = threadIdx.x, a = blockIdx.x;
    if (a >= nA) {  // W-conversion tail blocks
        int i = (a - nA) * 256 + t;
        if (i < DD * DD) {
            int c = i >> 7, k = i & 127;
            Wt[i] = f2bf(W[k * DD + c]);
        }
        return;
    }
    __shared__ int hist[256];
    int is64 = detect64(ei, E);
    if (t < NB) hist[t] = 0;
    __syncthreads();
    int base = a * EPB;
    #pragma unroll
    for (int it = 0; it < EPB / 256; ++it) {
        int e = base + it * 256 + t;
        if (e < E) {
            int s = ld_src(ei, e, E, is64);
            int d = ld_dst(ei, e, E, is64);
            outTail[e] = (float)s;
            outTail[E + e] = (float)d;
            atomicAdd(&hist[d >> BSH], 1);
        }
    }
    __syncthreads();
    if (t < NB) H[a * NB + t] = hist[t];
}

// ---------- scanH1: per-column exclusive scan of H (NB blocks, nA<=1024) ----------
__global__ __launch_bounds__(256) void k_scanH1(int* __restrict__ H, int nA, int NB,
                                                int* __restrict__ colsum) {
    __shared__ int s[256];
    int b = blockIdx.x, t = threadIdx.x;
    int K = (nA + 255) / 256;
    int base = t * K;
    int local = 0;
    for (int j = 0; j < K; ++j) {
        int a = base + j;
        if (a < nA) local += H[a * NB + b];
    }
    s[t] = local;
    __syncthreads();
    #pragma unroll
    for (int off = 1; off < 256; off <<= 1) {
        int u = (t >= off) ? s[t - off] : 0;
        __syncthreads();
        s[t] += u;
        __syncthreads();
    }
    int run = s[t] - local;  // exclusive prefix of this thread's chunk
    for (int j = 0; j < K; ++j) {
        int a = base + j;
        if (a < nA) { int v = H[a * NB + b]; H[a * NB + b] = run; run += v; }
    }
    if (t == 255) colsum[b] = s[255];
}

// ---------- A2: scatter packed records; bucketstart derived locally from colsum ----
// record = src | (dst&511)<<17   (needs N <= 131072)
__global__ __launch_bounds__(256) void kA2(const int* __restrict__ ei, int E, int NB,
                                           const int* __restrict__ H,
                                           const int* __restrict__ colsum,
                                           unsigned* __restrict__ brec) {
    __shared__ int bs[256];
    __shared__ int cur[256];
    int t = threadIdx.x, a = blockIdx.x;
    int is64 = detect64(ei, E);
    int v = (t < NB) ? colsum[t] : 0;
    bs[t] = v;
    __syncthreads();
    #pragma unroll
    for (int off = 1; off < 256; off <<= 1) {
        int u = (t >= off) ? bs[t - off] : 0;
        __syncthreads();
        bs[t] += u;
        __syncthreads();
    }
    if (t < NB) cur[t] = H[a * NB + t] + bs[t] - v;  // exclusive bucketstart + block offset
    __syncthreads();
    int base = a * EPB;
    #pragma unroll
    for (int it = 0; it < EPB / 256; ++it) {
        int e = base + it * 256 + t;
        if (e < E) {
            int s = ld_src(ei, e, E, is64);
            int d = ld_dst(ei, e, E, is64);
            int pos = atomicAdd(&cur[d >> BSH], 1);  // LDS atomic
            brec[pos] = (unsigned)s | ((unsigned)(d & 511) << 17);
        }
    }
}

// ---------- B: per-bucket CSR finalize (512 threads, parallel scans) ----------
__global__ __launch_bounds__(512) void kB(const unsigned* __restrict__ brec,
                                          const int* __restrict__ colsum, int NB, int N,
                                          int E, unsigned* __restrict__ recs,
                                          int* __restrict__ rowstart, float* __restrict__ invs) {
    __shared__ int bs[256];
    __shared__ int hist[512];
    __shared__ int scn[512];
    __shared__ int cur[512];
    int b = blockIdx.x, t = threadIdx.x;
    if (t < 256) bs[t] = (t < NB) ? colsum[t] : 0;
    __syncthreads();
    #pragma unroll
    for (int off = 1; off < 256; off <<= 1) {
        int u = 0;
        if (t < 256 && t >= off) u = bs[t - off];
        __syncthreads();
        if (t < 256) bs[t] += u;
        __syncthreads();
    }
    int cs = colsum[b];
    int hi = bs[b];          // inclusive
    int lo = hi - cs;        // exclusive
    hist[t] = 0;
    __syncthreads();
    for (int i = lo + t; i < hi; i += 512) atomicAdd(&hist[brec[i] >> 17], 1);
    __syncthreads();
    int hv = hist[t];
    scn[t] = hv;
    __syncthreads();
    #pragma unroll
    for (int off = 1; off < 512; off <<= 1) {
        int u = (t >= off) ? scn[t - off] : 0;
        __syncthreads();
        scn[t] += u;
        __syncthreads();
    }
    int excl = scn[t] - hv;
    int node = (b << BSH) + t;
    if (node < N) {
        rowstart[node] = lo + excl;
        invs[node] = rsqrtf((float)(1 + hv));  // deg includes self-loop
    }
    cur[t] = lo + excl;
    if (b == NB - 1 && t == 0) rowstart[N] = E;
    __syncthreads();
    for (int i = lo + t; i < hi; i += 512) {
        unsigned r = brec[i];
        int pos = atomicAdd(&cur[r >> 17], 1);  // LDS atomic
        recs[pos] = r & 0x1FFFFu;
    }
}

// ---------- k_gemm_h: h = quant( invs[node] * (x W) )  (swapped-operand MFMA) ----------
// FP8: hs row = 32 uints (128 fp8). BF16 fallback: hs row = 64 uints (128 bf16).
__global__ __launch_bounds__(256) void k_gemm_h(const float* __restrict__ x,
                                                const ushort* __restrict__ Wt,
                                                const float* __restrict__ invs,
                                                unsigned* __restrict__ hs, int N) {
    int wave = threadIdx.x >> 6, lane = threadIdx.x & 63;
    int rowBase = blockIdx.x * 64 + wave * 16;
    int rfrag = lane & 15, kgrp = lane >> 4;
    f32x4 zero = {0.f, 0.f, 0.f, 0.f};
    f32x4 acc[8];
    #pragma unroll
    for (int n = 0; n < 8; ++n) acc[n] = zero;

    int arow = rowBase + rfrag;
    bool av = arow < N;
    const float* xrow = x + (size_t)(av ? arow : 0) * DD + kgrp * 8;
    const ushort* wbase = Wt + rfrag * DD + kgrp * 8;

    #pragma unroll
    for (int ks = 0; ks < 4; ++ks) {
        bf16x8 bnode = {0, 0, 0, 0, 0, 0, 0, 0};
        if (av) {
            float4 f0 = *(const float4*)(xrow + ks * 32);
            float4 f1 = *(const float4*)(xrow + ks * 32 + 4);
            bnode[0] = (short)f2bf(f0.x); bnode[1] = (short)f2bf(f0.y);
            bnode[2] = (short)f2bf(f0.z); bnode[3] = (short)f2bf(f0.w);
            bnode[4] = (short)f2bf(f1.x); bnode[5] = (short)f2bf(f1.y);
            bnode[6] = (short)f2bf(f1.z); bnode[7] = (short)f2bf(f1.w);
        }
        #pragma unroll
        for (int n = 0; n < 8; ++n) {
            bf16x8 aw = *(const bf16x8*)(wbase + n * 16 * DD + ks * 32);
            acc[n] = __builtin_amdgcn_mfma_f32_16x16x32_bf16(aw, bnode, acc[n], 0, 0, 0);
        }
    }

    int node = rowBase + rfrag;
    if (node < N) {
        float wn = invs[node];
        int csub = kgrp * 4;
#if FP8PATH
        #pragma unroll
        for (int n = 0; n < 8; ++n) {
            int c0 = n * 16 + csub;
            int u = __builtin_amdgcn_cvt_pk_fp8_f32(wn * acc[n][0], wn * acc[n][1], 0, false);
            u = __builtin_amdgcn_cvt_pk_fp8_f32(wn * acc[n][2], wn * acc[n][3], u, true);
            hs[(size_t)node * 32 + (c0 >> 2)] = (unsigned)u;
        }
#else
        #pragma unroll
        for (int n = 0; n < 8; ++n) {
            int c0 = n * 16 + csub;
            uint2 u;
            u.x = (unsigned)f2bf(wn * acc[n][0]) | ((unsigned)f2bf(wn * acc[n][1]) << 16);
            u.y = (unsigned)f2bf(wn * acc[n][2]) | ((unsigned)f2bf(wn * acc[n][3]) << 16);
            *(uint2*)&hs[(size_t)node * 64 + (c0 >> 1)] = u;
        }
#endif
    }
}

// ---------- k_agg_out: gather h rows, fused relu+bias+residual epilogue ----------
__global__ void k_agg_out(const unsigned* __restrict__ hs, const int* __restrict__ rowstart,
                          const float* __restrict__ invs, const unsigned* __restrict__ recs,
                          const float* __restrict__ bb, const float* __restrict__ x,
                          float* __restrict__ out, int N) {
    int node = blockIdx.x * 4 + (threadIdx.x >> 6);
    int lane = threadIdx.x & 63;
    if (node >= N) return;
    float wn = invs[node];
    float accx, accy;
    int e = rowstart[node], e1 = rowstart[node + 1];
#if FP8PATH
    const ushort* h16 = (const ushort*)hs;
    {
        f32x2 f = __builtin_amdgcn_cvt_pk_f32_fp8((int)(unsigned)h16[(size_t)node * 64 + lane], false);
        accx = f.x; accy = f.y;  // self term
    }
    for (; e + 16 <= e1; e += 16) {
        unsigned sv[16]; ushort vv[16];
        #pragma unroll
        for (int j = 0; j < 16; ++j) sv[j] = recs[e + j];
        #pragma unroll
        for (int j = 0; j < 16; ++j) vv[j] = h16[(size_t)sv[j] * 64 + lane];
        #pragma unroll
        for (int j = 0; j < 16; ++j) {
            f32x2 f = __builtin_amdgcn_cvt_pk_f32_fp8((int)(unsigned)vv[j], false);
            accx += f.x; accy += f.y;
        }
    }
    if (e + 8 <= e1) {
        unsigned sv[8]; ushort vv[8];
        #pragma unroll
        for (int j = 0; j < 8; ++j) sv[j] = recs[e + j];
        #pragma unroll
        for (int j = 0; j < 8; ++j) vv[j] = h16[(size_t)sv[j] * 64 + lane];
        #pragma unroll
        for (int j = 0; j < 8; ++j) {
            f32x2 f = __builtin_amdgcn_cvt_pk_f32_fp8((int)(unsigned)vv[j], false);
            accx += f.x; accy += f.y;
        }
        e += 8;
    }
    for (; e < e1; ++e) {
        f32x2 f = __builtin_amdgcn_cvt_pk_f32_fp8((int)(unsigned)h16[(size_t)recs[e] * 64 + lane], false);
        accx += f.x; accy += f.y;
    }
#else
    {
        unsigned us = hs[(size_t)node * 64 + lane];
        accx = bflo(us); accy = bfhi(us);
    }
    for (; e + 16 <= e1; e += 16) {
        unsigned sv[16], vv[16];
        #pragma unroll
        for (int j = 0; j < 16; ++j) sv[j] = recs[e + j];
        #pragma unroll
        for (int j = 0; j < 16; ++j) vv[j] = hs[(size_t)sv[j] * 64 + lane];
        #pragma unroll
        for (int j = 0; j < 16; ++j) { accx += bflo(vv[j]); accy += bfhi(vv[j]); }
    }
    if (e + 8 <= e1) {
        unsigned sv[8], vv[8];
        #pragma unroll
        for (int j = 0; j < 8; ++j) sv[j] = recs[e + j];
        #pragma unroll
        for (int j = 0; j < 8; ++j) vv[j] = hs[(size_t)sv[j] * 64 + lane];
        #pragma unroll
        for (int j = 0; j < 8; ++j) { accx += bflo(vv[j]); accy += bfhi(vv[j]); }
        e += 8;
    }
    for (; e < e1; ++e) {
        unsigned v0 = hs[(size_t)recs[e] * 64 + lane];
        accx += bflo(v0); accy += bfhi(v0);
    }
#endif
    float2 bv = ((const float2*)bb)[lane];
    float2 xv = ((const float2*)x)[(size_t)node * 64 + lane];
    float2 o;
    o.x = fmaxf(accx * wn + bv.x, 0.f) + xv.x;
    o.y = fmaxf(accy * wn + bv.y, 0.f) + xv.y;
    ((float2*)out)[(size_t)node * 64 + lane] = o;
}

// =================== fallback path (shape/ws outside new-path limits) ===================
__global__ void k_sniff(const int* __restrict__ p, int n_check, int* __restrict__ flag) {
    __shared__ int any_nonzero;
    if (threadIdx.x == 0) any_nonzero = 0;
    __syncthreads();
    int j = threadIdx.x;
    if (j < n_check && p[2 * j + 1] != 0) any_nonzero = 1;
    __syncthreads();
    if (threadIdx.x == 0) *flag = any_nonzero ? 0 : 1;
}

__global__ void k_count_echo(const int* __restrict__ ei, int E, int* __restrict__ cnt,
                             float* __restrict__ outTail, unsigned* __restrict__ rank,
                             const int* __restrict__ flagp) {
    int is64 = *flagp;
    int e = blockIdx.x * blockDim.x + threadIdx.x;
    if (e < E) {
        int s = ld_src(ei, e, E, is64);
        int d = ld_dst(ei, e, E, is64);
        outTail[e] = (float)s;
        outTail[E + e] = (float)d;
        rank[e] = (unsigned)atomicAdd(&cnt[d], 1);
    }
}

__global__ void k_scan1(const int* __restrict__ cnt, int N, int* __restrict__ rowstart,
                        int* __restrict__ bsum) {
    __shared__ int s[1024];
    int tid = threadIdx.x;
    int i = blockIdx.x * 1024 + tid;
    int v = (i < N) ? cnt[i] : 0;
    s[tid] = v;
    __syncthreads();
    for (int off = 1; off < 1024; off <<= 1) {
        int t2 = (tid >= off) ? s[tid - off] : 0;
        __syncthreads();
        s[tid] += t2;
        __syncthreads();
    }
    if (i < N) rowstart[i] = s[tid] - v;
    if (tid == 1023) bsum[blockIdx.x] = s[1023];
}

__global__ void k_scan2(const int* __restrict__ bsum, int nblk, int* __restrict__ boff) {
    __shared__ int s[128];
    int t = threadIdx.x;
    if (t < nblk) s[t] = bsum[t];
    __syncthreads();
    if (t == 0) {
        int a = 0;
        for (int i = 0; i < nblk; i++) { int v = s[i]; s[i] = a; a += v; }
    }
    __syncthreads();
    if (t < nblk) boff[t] = s[t];
}

__global__ void k_scan3(int N, int E, int* __restrict__ rowstart, const int* __restrict__ boff,
                        const int* __restrict__ cnt, float* __restrict__ invs) {
    int i = blockIdx.x * blockDim.x + threadIdx.x;
    if (i < N) {
        int r = rowstart[i] + boff[i >> 10];
        rowstart[i] = r;
        invs[i] = rsqrtf((float)(1 + cnt[i]));
    }
    if (i == 0 && blockIdx.x == 0) rowstart[N] = E;
}

__global__ void k_fill_r(const int* __restrict__ ei, int E, const int* __restrict__ rowstart,
                         const unsigned* __restrict__ rank, unsigned* __restrict__ recs,
                         const int* __restrict__ flagp) {
    int is64 = *flagp;
    int e = blockIdx.x * blockDim.x + threadIdx.x;
    if (e < E) {
        int d = ld_dst(ei, e, E, is64);
        int s = ld_src(ei, e, E, is64);
        recs[rowstart[d] + rank[e]] = (unsigned)s;
    }
}

__global__ void k_agg_f32(const float* __restrict__ x, const int* __restrict__ rowstart,
                          const float* __restrict__ invs, const unsigned* __restrict__ recs,
                          int N, float* __restrict__ aggOut) {
    int node = blockIdx.x * 4 + (threadIdx.x >> 6);
    int lane = threadIdx.x & 63;
    if (node >= N) return;
    const float2* xr = (const float2*)x;
    float wn = invs[node];
    float2 xself = xr[(size_t)node * 64 + lane];
    float accx = wn * xself.x, accy = wn * xself.y;
    int e = rowstart[node], e1 = rowstart[node + 1];
    for (; e < e1; ++e) {
        unsigned s = recs[e];
        float w = invs[s];
        float2 v = xr[(size_t)s * 64 + lane];
        accx = fmaf(w, v.x, accx); accy = fmaf(w, v.y, accy);
    }
    float2 o; o.x = accx * wn; o.y = accy * wn;
    ((float2*)aggOut)[(size_t)node * 64 + lane] = o;
}

#define GROWS 32
__global__ __launch_bounds__(128) void k_gemm_f32(float* __restrict__ out, const float* __restrict__ Wm,
                                                  const float* __restrict__ bb,
                                                  const float* __restrict__ x, int N) {
    __shared__ float Ws[64 * DD];
    __shared__ float As[DD * GROWS];
    int t = threadIdx.x;
    int rowBase = blockIdx.x * GROWS;
    {
        int r = t & 31, kq = t >> 5;
        if (rowBase + r < N) {
            const float4* Av = (const float4*)(out + (size_t)(rowBase + r) * DD);
            #pragma unroll
            for (int q = 0; q < 8; q++) {
                float4 v = Av[kq * 8 + q];
                int k = (kq * 8 + q) * 4;
                As[(k + 0) * GROWS + r] = v.x;
                As[(k + 1) * GROWS + r] = v.y;
                As[(k + 2) * GROWS + r] = v.z;
                As[(k + 3) * GROWS + r] = v.w;
            }
        } else {
            #pragma unroll
            for (int q = 0; q < 8; q++) {
                int k = (kq * 8 + q) * 4;
                As[(k + 0) * GROWS + r] = 0.f;
                As[(k + 1) * GROWS + r] = 0.f;
                As[(k + 2) * GROWS + r] = 0.f;
                As[(k + 3) * GROWS + r] = 0.f;
            }
        }
    }
    int tx = t & 15, ty = t >> 4;
    int c0 = tx * 8, r0 = ty * 4;
    float acc[4][8];
    #pragma unroll
    for (int i = 0; i < 4; i++)
        #pragma unroll
        for (int j = 0; j < 8; j++) acc[i][j] = 0.f;
    for (int kk = 0; kk < DD; kk += 64) {
        __syncthreads();
        const float4* Wv = (const float4*)(Wm + (size_t)kk * DD);
        #pragma unroll
        for (int i = 0; i < 16; i++) ((float4*)Ws)[t + i * 128] = Wv[t + i * 128];
        __syncthreads();
        #pragma unroll 4
        for (int k = 0; k < 64; k++) {
            const float4 a = *(const float4*)&As[(kk + k) * GROWS + r0];
            const float4 w0 = *(const float4*)&Ws[k * DD + c0];
            const float4 w1 = *(const float4*)&Ws[k * DD + c0 + 4];
            const float av[4] = {a.x, a.y, a.z, a.w};
            const float wv[8] = {w0.x, w0.y, w0.z, w0.w, w1.x, w1.y, w1.z, w1.w};
            #pragma unroll
            for (int i = 0; i < 4; i++)
                #pragma unroll
                for (int j = 0; j < 8; j++) acc[i][j] = fmaf(av[i], wv[j], acc[i][j]);
        }
    }
    float bv[8];
    {
        float4 b0 = *(const float4*)&bb[c0];
        float4 b1 = *(const float4*)&bb[c0 + 4];
        bv[0] = b0.x; bv[1] = b0.y; bv[2] = b0.z; bv[3] = b0.w;
        bv[4] = b1.x; bv[5] = b1.y; bv[6] = b1.z; bv[7] = b1.w;
    }
    #pragma unroll
    for (int i = 0; i < 4; i++) {
        int row = rowBase + r0 + i;
        if (row < N) {
            const float4 xv0 = *(const float4*)&x[(size_t)row * DD + c0];
            const float4 xv1 = *(const float4*)&x[(size_t)row * DD + c0 + 4];
            float4 o0, o1;
            o0.x = fmaxf(acc[i][0] + bv[0], 0.f) + xv0.x;
            o0.y = fmaxf(acc[i][1] + bv[1], 0.f) + xv0.y;
            o0.z = fmaxf(acc[i][2] + bv[2], 0.f) + xv0.z;
            o0.w = fmaxf(acc[i][3] + bv[3], 0.f) + xv0.w;
            o1.x = fmaxf(acc[i][4] + bv[4], 0.f) + xv1.x;
            o1.y = fmaxf(acc[i][5] + bv[5], 0.f) + xv1.y;
            o1.z = fmaxf(acc[i][6] + bv[6], 0.f) + xv1.z;
            o1.w = fmaxf(acc[i][7] + bv[7], 0.f) + xv1.w;
            *(float4*)&out[(size_t)row * DD + c0] = o0;
            *(float4*)&out[(size_t)row * DD + c0 + 4] = o1;
        }
    }
}

extern "C" void kernel_launch(void* const* d_in, const int* in_sizes, int n_in,
                              void* d_out, int out_size, void* d_ws, size_t ws_size,
                              hipStream_t stream) {
    const float* x = (const float*)d_in[0];
    const float* W = (const float*)d_in[1];
    const float* b = (const float*)d_in[2];
    const int*   ei = (const int*)d_in[3];
    int N = in_sizes[0] / DD;
    int E = in_sizes[3] / 2;
    float* out = (float*)d_out;
    float* outTail = out + (size_t)N * DD;

    int NB = (N + 511) >> BSH;          // buckets of 512 nodes
    int nA = (E + EPB - 1) / EPB;       // A-pass blocks

    // new-path workspace layout (hs sized for bf16 fallback = superset of fp8)
    char* wsb = (char*)d_ws;
    size_t off = 0;
    unsigned* brec = (unsigned*)(wsb + off);  off += (size_t)E * 4;
    unsigned* recs = (unsigned*)(wsb + off);  off += (size_t)E * 4;
    unsigned* hs   = (unsigned*)(wsb + off);  off += (size_t)N * 64 * 4;
    ushort*   Wt   = (ushort*)(wsb + off);    off += (size_t)DD * DD * 2;
    int* H         = (int*)(wsb + off);       off += (size_t)nA * NB * 4;
    int* colsum    = (int*)(wsb + off);       off += (size_t)NB * 4;
    int* rowstart  = (int*)(wsb + off);       off += (size_t)(N + 1) * 4;
    float* invs    = (float*)(wsb + off);     off += (size_t)N * 4;

    bool newpath = (ws_size >= off) && (NB <= 256) && (nA <= 1024) && (N <= 131072) && (E >= 64);

    if (newpath) {
        kA1<<<nA + 64, 256, 0, stream>>>(ei, E, NB, nA, outTail, H, W, Wt);
        k_scanH1<<<NB, 256, 0, stream>>>(H, nA, NB, colsum);
        kA2<<<nA, 256, 0, stream>>>(ei, E, NB, H, colsum, brec);
        kB<<<NB, 512, 0, stream>>>(brec, colsum, NB, N, E, recs, rowstart, invs);
        k_gemm_h<<<(N + 63) / 64, 256, 0, stream>>>(x, Wt, invs, hs, N);
        k_agg_out<<<(N + 3) / 4, 256, 0, stream>>>(hs, rowstart, invs, recs, b, x, out, N);
    } else {
        // fallback: rank-based build + f32 compute (known good)
        off = 0;
        unsigned* recsF = (unsigned*)(wsb + off);  off += (size_t)E * 4;
        unsigned* rank  = (unsigned*)(wsb + off);  off += (size_t)E * 4;
        int* cnt        = (int*)(wsb + off);       off += (size_t)N * 4;
        int* rowstartF  = (int*)(wsb + off);       off += (size_t)(N + 1) * 4;
        float* invsF    = (float*)(wsb + off);     off += (size_t)N * 4;
        int* bsum       = (int*)(wsb + off);       off += 512 * 4;
        int* boff       = (int*)(wsb + off);       off += 512 * 4;
        int* flagF      = (int*)(wsb + off);

        hipMemsetAsync(cnt, 0, sizeof(int) * (size_t)N, stream);
        k_sniff<<<1, 1024, 0, stream>>>(ei, 1024, flagF);
        k_count_echo<<<(E + 255) / 256, 256, 0, stream>>>(ei, E, cnt, outTail, rank, flagF);
        int nblk = (N + 1023) / 1024;
        k_scan1<<<nblk, 1024, 0, stream>>>(cnt, N, rowstartF, bsum);
        k_scan2<<<1, 128, 0, stream>>>(bsum, nblk, boff);
        k_scan3<<<(N + 255) / 256, 256, 0, stream>>>(N, E, rowstartF, boff, cnt, invsF);
        k_fill_r<<<(E + 255) / 256, 256, 0, stream>>>(ei, E, rowstartF, rank, recsF, flagF);
        k_agg_f32<<<(N + 3) / 4, 256, 0, stream>>>(x, rowstartF, invsF, recsF, N, out);
        k_gemm_f32<<<(N + GROWS - 1) / GROWS, 128, 0, stream>>>(out, W, b, x, N);
    }
}

// Round 15
// 151.746 us; speedup vs baseline: 2.1505x; 1.0110x over previous
//
#include <hip/hip_runtime.h>

// GCNBlock: out0 = relu( (D^-1/2 (A+I) D^-1/2) (x W) + b ) + x   [N,128] f32
//           out1 = edge_index echoed (as float values) appended in d_out
// Round 15: k_agg_out pairs 2 nodes per wave (interleaved 8+8 gather batches)
// to raise outstanding HBM misses per wave — round-14 showed the gather is
// miss-capacity bound (FETCH halved, dur only -13%). Everything else as r14.

#define DD 128
#define EPB 2048      // edges per A-block (8 iters x 256 threads)
#define BSH 9         // bucket shift: 512 nodes per bucket
typedef __attribute__((ext_vector_type(8))) short bf16x8;
typedef __attribute__((ext_vector_type(4))) float f32x4;
typedef __attribute__((ext_vector_type(2))) float f32x2;

#if __has_builtin(__builtin_amdgcn_cvt_pk_fp8_f32) && __has_builtin(__builtin_amdgcn_cvt_pk_f32_fp8)
#define FP8PATH 1
#else
#define FP8PATH 0
#endif

__device__ __forceinline__ ushort f2bf(float f) {
    unsigned u = __float_as_uint(f);
    unsigned r = (u + 0x7fffu + ((u >> 16) & 1u)) >> 16;  // RNE
    return (ushort)r;
}
__device__ __forceinline__ float bflo(unsigned u) { return __uint_as_float(u << 16); }
__device__ __forceinline__ float bfhi(unsigned u) { return __uint_as_float(u & 0xffff0000u); }

__device__ __forceinline__ int ld_src(const int* p, int e, int E, int is64) {
    return is64 ? p[2 * e] : p[e];
}
__device__ __forceinline__ int ld_dst(const int* p, int e, int E, int is64) {
    return is64 ? p[2 * (E + e)] : p[E + e];
}

// inline dtype sniff: int64 edge data has all-zero high words.
__device__ __forceinline__ int detect64(const int* __restrict__ p, int E) {
    int lane = threadIdx.x & 63;
    int idx = 2 * lane + 1;
    if (idx >= 2 * E) idx = 2 * E - 1;
    unsigned long long m = __ballot(p[idx] != 0);
    return m == 0ull ? 1 : 0;
}

// ---------- A1: bucket histogram + fused echo (+ tail blocks convert W) ----------
__global__ __launch_bounds__(256) void kA1(const int* __restrict__ ei, int E, int NB, int nA,
                                           float* __restrict__ outTail, int* __restrict__ H,
                                           const float* __restrict__ W, ushort* __restrict__ Wt) {
    int t = threadIdx.x, a = blockIdx.x;
    if (a >= nA) {  // W-conversion tail blocks
        int i = (a - nA) * 256 + t;
        if (i < DD * DD) {
            int c = i >> 7, k = i & 127;
            Wt[i] = f2bf(W[k * DD + c]);
        }
        return;
    }
    __shared__ int hist[256];
    int is64 = detect64(ei, E);
    if (t < NB) hist[t] = 0;
    __syncthreads();
    int base = a * EPB;
    #pragma unroll
    for (int it = 0; it < EPB / 256; ++it) {
        int e = base + it * 256 + t;
        if (e < E) {
            int s = ld_src(ei, e, E, is64);
            int d = ld_dst(ei, e, E, is64);
            outTail[e] = (float)s;
            outTail[E + e] = (float)d;
            atomicAdd(&hist[d >> BSH], 1);
        }
    }
    __syncthreads();
    if (t < NB) H[a * NB + t] = hist[t];
}

// ---------- scanH1: per-column exclusive scan of H (NB blocks, nA<=1024) ----------
__global__ __launch_bounds__(256) void k_scanH1(int* __restrict__ H, int nA, int NB,
                                                int* __restrict__ colsum) {
    __shared__ int s[256];
    int b = blockIdx.x, t = threadIdx.x;
    int K = (nA + 255) / 256;
    int base = t * K;
    int local = 0;
    for (int j = 0; j < K; ++j) {
        int a = base + j;
        if (a < nA) local += H[a * NB + b];
    }
    s[t] = local;
    __syncthreads();
    #pragma unroll
    for (int off = 1; off < 256; off <<= 1) {
        int u = (t >= off) ? s[t - off] : 0;
        __syncthreads();
        s[t] += u;
        __syncthreads();
    }
    int run = s[t] - local;  // exclusive prefix of this thread's chunk
    for (int j = 0; j < K; ++j) {
        int a = base + j;
        if (a < nA) { int v = H[a * NB + b]; H[a * NB + b] = run; run += v; }
    }
    if (t == 255) colsum[b] = s[255];
}

// ---------- A2: scatter packed records; bucketstart derived locally from colsum ----
// record = src | (dst&511)<<17   (needs N <= 131072)
__global__ __launch_bounds__(256) void kA2(const int* __restrict__ ei, int E, int NB,
                                           const int* __restrict__ H,
                                           const int* __restrict__ colsum,
                                           unsigned* __restrict__ brec) {
    __shared__ int bs[256];
    __shared__ int cur[256];
    int t = threadIdx.x, a = blockIdx.x;
    int is64 = detect64(ei, E);
    int v = (t < NB) ? colsum[t] : 0;
    bs[t] = v;
    __syncthreads();
    #pragma unroll
    for (int off = 1; off < 256; off <<= 1) {
        int u = (t >= off) ? bs[t - off] : 0;
        __syncthreads();
        bs[t] += u;
        __syncthreads();
    }
    if (t < NB) cur[t] = H[a * NB + t] + bs[t] - v;  // exclusive bucketstart + block offset
    __syncthreads();
    int base = a * EPB;
    #pragma unroll
    for (int it = 0; it < EPB / 256; ++it) {
        int e = base + it * 256 + t;
        if (e < E) {
            int s = ld_src(ei, e, E, is64);
            int d = ld_dst(ei, e, E, is64);
            int pos = atomicAdd(&cur[d >> BSH], 1);  // LDS atomic
            brec[pos] = (unsigned)s | ((unsigned)(d & 511) << 17);
        }
    }
}

// ---------- B: per-bucket CSR finalize (512 threads, parallel scans) ----------
__global__ __launch_bounds__(512) void kB(const unsigned* __restrict__ brec,
                                          const int* __restrict__ colsum, int NB, int N,
                                          int E, unsigned* __restrict__ recs,
                                          int* __restrict__ rowstart, float* __restrict__ invs) {
    __shared__ int bs[256];
    __shared__ int hist[512];
    __shared__ int scn[512];
    __shared__ int cur[512];
    int b = blockIdx.x, t = threadIdx.x;
    if (t < 256) bs[t] = (t < NB) ? colsum[t] : 0;
    __syncthreads();
    #pragma unroll
    for (int off = 1; off < 256; off <<= 1) {
        int u = 0;
        if (t < 256 && t >= off) u = bs[t - off];
        __syncthreads();
        if (t < 256) bs[t] += u;
        __syncthreads();
    }
    int cs = colsum[b];
    int hi = bs[b];          // inclusive
    int lo = hi - cs;        // exclusive
    hist[t] = 0;
    __syncthreads();
    for (int i = lo + t; i < hi; i += 512) atomicAdd(&hist[brec[i] >> 17], 1);
    __syncthreads();
    int hv = hist[t];
    scn[t] = hv;
    __syncthreads();
    #pragma unroll
    for (int off = 1; off < 512; off <<= 1) {
        int u = (t >= off) ? scn[t - off] : 0;
        __syncthreads();
        scn[t] += u;
        __syncthreads();
    }
    int excl = scn[t] - hv;
    int node = (b << BSH) + t;
    if (node < N) {
        rowstart[node] = lo + excl;
        invs[node] = rsqrtf((float)(1 + hv));  // deg includes self-loop
    }
    cur[t] = lo + excl;
    if (b == NB - 1 && t == 0) rowstart[N] = E;
    __syncthreads();
    for (int i = lo + t; i < hi; i += 512) {
        unsigned r = brec[i];
        int pos = atomicAdd(&cur[r >> 17], 1);  // LDS atomic
        recs[pos] = r & 0x1FFFFu;
    }
}

// ---------- k_gemm_h: h = quant( invs[node] * (x W) )  (swapped-operand MFMA) ----------
__global__ __launch_bounds__(256) void k_gemm_h(const float* __restrict__ x,
                                                const ushort* __restrict__ Wt,
                                                const float* __restrict__ invs,
                                                unsigned* __restrict__ hs, int N) {
    int wave = threadIdx.x >> 6, lane = threadIdx.x & 63;
    int rowBase = blockIdx.x * 64 + wave * 16;
    int rfrag = lane & 15, kgrp = lane >> 4;
    f32x4 zero = {0.f, 0.f, 0.f, 0.f};
    f32x4 acc[8];
    #pragma unroll
    for (int n = 0; n < 8; ++n) acc[n] = zero;

    int arow = rowBase + rfrag;
    bool av = arow < N;
    const float* xrow = x + (size_t)(av ? arow : 0) * DD + kgrp * 8;
    const ushort* wbase = Wt + rfrag * DD + kgrp * 8;

    #pragma unroll
    for (int ks = 0; ks < 4; ++ks) {
        bf16x8 bnode = {0, 0, 0, 0, 0, 0, 0, 0};
        if (av) {
            float4 f0 = *(const float4*)(xrow + ks * 32);
            float4 f1 = *(const float4*)(xrow + ks * 32 + 4);
            bnode[0] = (short)f2bf(f0.x); bnode[1] = (short)f2bf(f0.y);
            bnode[2] = (short)f2bf(f0.z); bnode[3] = (short)f2bf(f0.w);
            bnode[4] = (short)f2bf(f1.x); bnode[5] = (short)f2bf(f1.y);
            bnode[6] = (short)f2bf(f1.z); bnode[7] = (short)f2bf(f1.w);
        }
        #pragma unroll
        for (int n = 0; n < 8; ++n) {
            bf16x8 aw = *(const bf16x8*)(wbase + n * 16 * DD + ks * 32);
            acc[n] = __builtin_amdgcn_mfma_f32_16x16x32_bf16(aw, bnode, acc[n], 0, 0, 0);
        }
    }

    int node = rowBase + rfrag;
    if (node < N) {
        float wn = invs[node];
        int csub = kgrp * 4;
#if FP8PATH
        #pragma unroll
        for (int n = 0; n < 8; ++n) {
            int c0 = n * 16 + csub;
            int u = __builtin_amdgcn_cvt_pk_fp8_f32(wn * acc[n][0], wn * acc[n][1], 0, false);
            u = __builtin_amdgcn_cvt_pk_fp8_f32(wn * acc[n][2], wn * acc[n][3], u, true);
            hs[(size_t)node * 32 + (c0 >> 2)] = (unsigned)u;
        }
#else
        #pragma unroll
        for (int n = 0; n < 8; ++n) {
            int c0 = n * 16 + csub;
            uint2 u;
            u.x = (unsigned)f2bf(wn * acc[n][0]) | ((unsigned)f2bf(wn * acc[n][1]) << 16);
            u.y = (unsigned)f2bf(wn * acc[n][2]) | ((unsigned)f2bf(wn * acc[n][3]) << 16);
            *(uint2*)&hs[(size_t)node * 64 + (c0 >> 1)] = u;
        }
#endif
    }
}

// ---------- k_agg_out: 2 nodes/wave, interleaved gathers, fused epilogue ----------
#if FP8PATH
__device__ __forceinline__ void agg_batch16_fp8(const ushort* h16, const unsigned* recs,
                                                int e, int lane, float& ax, float& ay) {
    unsigned sv[16]; ushort vv[16];
    #pragma unroll
    for (int j = 0; j < 16; ++j) sv[j] = recs[e + j];
    #pragma unroll
    for (int j = 0; j < 16; ++j) vv[j] = h16[(size_t)sv[j] * 64 + lane];
    #pragma unroll
    for (int j = 0; j < 16; ++j) {
        f32x2 f = __builtin_amdgcn_cvt_pk_f32_fp8((int)(unsigned)vv[j], false);
        ax += f.x; ay += f.y;
    }
}
__device__ __forceinline__ void agg_batch8_fp8(const ushort* h16, const unsigned* recs,
                                               int e, int lane, float& ax, float& ay) {
    unsigned sv[8]; ushort vv[8];
    #pragma unroll
    for (int j = 0; j < 8; ++j) sv[j] = recs[e + j];
    #pragma unroll
    for (int j = 0; j < 8; ++j) vv[j] = h16[(size_t)sv[j] * 64 + lane];
    #pragma unroll
    for (int j = 0; j < 8; ++j) {
        f32x2 f = __builtin_amdgcn_cvt_pk_f32_fp8((int)(unsigned)vv[j], false);
        ax += f.x; ay += f.y;
    }
}
#endif

__global__ __launch_bounds__(256) void k_agg_out(const unsigned* __restrict__ hs,
                                                 const int* __restrict__ rowstart,
                                                 const float* __restrict__ invs,
                                                 const unsigned* __restrict__ recs,
                                                 const float* __restrict__ bb,
                                                 const float* __restrict__ x,
                                                 float* __restrict__ out, int N) {
    int wave = threadIdx.x >> 6, lane = threadIdx.x & 63;
#if FP8PATH
    int nodeA = blockIdx.x * 8 + wave * 2;
    if (nodeA >= N) return;
    int nodeB = nodeA + 1;
    bool hasB = nodeB < N;
    const ushort* h16 = (const ushort*)hs;
    float axA, ayA, axB = 0.f, ayB = 0.f;
    {
        f32x2 f = __builtin_amdgcn_cvt_pk_f32_fp8((int)(unsigned)h16[(size_t)nodeA * 64 + lane], false);
        axA = f.x; ayA = f.y;  // self term A
    }
    int eA = rowstart[nodeA], eA1 = rowstart[nodeA + 1];
    int eB = eA1, eB1 = eA1;
    if (hasB) {
        f32x2 f = __builtin_amdgcn_cvt_pk_f32_fp8((int)(unsigned)h16[(size_t)nodeB * 64 + lane], false);
        axB = f.x; ayB = f.y;  // self term B
        eB1 = rowstart[nodeB + 1];
    }
    // interleaved 8+8 (16 independent gathers in flight)
    while (eA + 8 <= eA1 && eB + 8 <= eB1) {
        unsigned svA[8], svB[8]; ushort vvA[8], vvB[8];
        #pragma unroll
        for (int j = 0; j < 8; ++j) svA[j] = recs[eA + j];
        #pragma unroll
        for (int j = 0; j < 8; ++j) svB[j] = recs[eB + j];
        #pragma unroll
        for (int j = 0; j < 8; ++j) vvA[j] = h16[(size_t)svA[j] * 64 + lane];
        #pragma unroll
        for (int j = 0; j < 8; ++j) vvB[j] = h16[(size_t)svB[j] * 64 + lane];
        #pragma unroll
        for (int j = 0; j < 8; ++j) {
            f32x2 f = __builtin_amdgcn_cvt_pk_f32_fp8((int)(unsigned)vvA[j], false);
            axA += f.x; ayA += f.y;
        }
        #pragma unroll
        for (int j = 0; j < 8; ++j) {
            f32x2 f = __builtin_amdgcn_cvt_pk_f32_fp8((int)(unsigned)vvB[j], false);
            axB += f.x; ayB += f.y;
        }
        eA += 8; eB += 8;
    }
    // drain A
    for (; eA + 16 <= eA1; eA += 16) agg_batch16_fp8(h16, recs, eA, lane, axA, ayA);
    if (eA + 8 <= eA1) { agg_batch8_fp8(h16, recs, eA, lane, axA, ayA); eA += 8; }
    for (; eA < eA1; ++eA) {
        f32x2 f = __builtin_amdgcn_cvt_pk_f32_fp8((int)(unsigned)h16[(size_t)recs[eA] * 64 + lane], false);
        axA += f.x; ayA += f.y;
    }
    // drain B
    for (; eB + 16 <= eB1; eB += 16) agg_batch16_fp8(h16, recs, eB, lane, axB, ayB);
    if (eB + 8 <= eB1) { agg_batch8_fp8(h16, recs, eB, lane, axB, ayB); eB += 8; }
    for (; eB < eB1; ++eB) {
        f32x2 f = __builtin_amdgcn_cvt_pk_f32_fp8((int)(unsigned)h16[(size_t)recs[eB] * 64 + lane], false);
        axB += f.x; ayB += f.y;
    }
    float2 bv = ((const float2*)bb)[lane];
    {
        float wn = invs[nodeA];
        float2 xv = ((const float2*)x)[(size_t)nodeA * 64 + lane];
        float2 o;
        o.x = fmaxf(axA * wn + bv.x, 0.f) + xv.x;
        o.y = fmaxf(ayA * wn + bv.y, 0.f) + xv.y;
        ((float2*)out)[(size_t)nodeA * 64 + lane] = o;
    }
    if (hasB) {
        float wn = invs[nodeB];
        float2 xv = ((const float2*)x)[(size_t)nodeB * 64 + lane];
        float2 o;
        o.x = fmaxf(axB * wn + bv.x, 0.f) + xv.x;
        o.y = fmaxf(ayB * wn + bv.y, 0.f) + xv.y;
        ((float2*)out)[(size_t)nodeB * 64 + lane] = o;
    }
#else
    // bf16 fallback: 2 nodes sequentially per wave (correctness path)
    int base = blockIdx.x * 8 + wave * 2;
    for (int node = base; node < base + 2 && node < N; ++node) {
        float wn = invs[node];
        unsigned us = hs[(size_t)node * 64 + lane];
        float accx = bflo(us), accy = bfhi(us);
        int e = rowstart[node], e1 = rowstart[node + 1];
        for (; e + 8 <= e1; e += 8) {
            unsigned sv[8], vv[8];
            #pragma unroll
            for (int j = 0; j < 8; ++j) sv[j] = recs[e + j];
            #pragma unroll
            for (int j = 0; j < 8; ++j) vv[j] = hs[(size_t)sv[j] * 64 + lane];
            #pragma unroll
            for (int j = 0; j < 8; ++j) { accx += bflo(vv[j]); accy += bfhi(vv[j]); }
        }
        for (; e < e1; ++e) {
            unsigned v0 = hs[(size_t)recs[e] * 64 + lane];
            accx += bflo(v0); accy += bfhi(v0);
        }
        float2 bv = ((const float2*)bb)[lane];
        float2 xv = ((const float2*)x)[(size_t)node * 64 + lane];
        float2 o;
        o.x = fmaxf(accx * wn + bv.x, 0.f) + xv.x;
        o.y = fmaxf(accy * wn + bv.y, 0.f) + xv.y;
        ((float2*)out)[(size_t)node * 64 + lane] = o;
    }
#endif
}

// =================== fallback path (shape/ws outside new-path limits) ===================
__global__ void k_sniff(const int* __restrict__ p, int n_check, int* __restrict__ flag) {
    __shared__ int any_nonzero;
    if (threadIdx.x == 0) any_nonzero = 0;
    __syncthreads();
    int j = threadIdx.x;
    if (j < n_check && p[2 * j + 1] != 0) any_nonzero = 1;
    __syncthreads();
    if (threadIdx.x == 0) *flag = any_nonzero ? 0 : 1;
}

__global__ void k_count_echo(const int* __restrict__ ei, int E, int* __restrict__ cnt,
                             float* __restrict__ outTail, unsigned* __restrict__ rank,
                             const int* __restrict__ flagp) {
    int is64 = *flagp;
    int e = blockIdx.x * blockDim.x + threadIdx.x;
    if (e < E) {
        int s = ld_src(ei, e, E, is64);
        int d = ld_dst(ei, e, E, is64);
        outTail[e] = (float)s;
        outTail[E + e] = (float)d;
        rank[e] = (unsigned)atomicAdd(&cnt[d], 1);
    }
}

__global__ void k_scan1(const int* __restrict__ cnt, int N, int* __restrict__ rowstart,
                        int* __restrict__ bsum) {
    __shared__ int s[1024];
    int tid = threadIdx.x;
    int i = blockIdx.x * 1024 + tid;
    int v = (i < N) ? cnt[i] : 0;
    s[tid] = v;
    __syncthreads();
    for (int off = 1; off < 1024; off <<= 1) {
        int t2 = (tid >= off) ? s[tid - off] : 0;
        __syncthreads();
        s[tid] += t2;
        __syncthreads();
    }
    if (i < N) rowstart[i] = s[tid] - v;
    if (tid == 1023) bsum[blockIdx.x] = s[1023];
}

__global__ void k_scan2(const int* __restrict__ bsum, int nblk, int* __restrict__ boff) {
    __shared__ int s[128];
    int t = threadIdx.x;
    if (t < nblk) s[t] = bsum[t];
    __syncthreads();
    if (t == 0) {
        int a = 0;
        for (int i = 0; i < nblk; i++) { int v = s[i]; s[i] = a; a += v; }
    }
    __syncthreads();
    if (t < nblk) boff[t] = s[t];
}

__global__ void k_scan3(int N, int E, int* __restrict__ rowstart, const int* __restrict__ boff,
                        const int* __restrict__ cnt, float* __restrict__ invs) {
    int i = blockIdx.x * blockDim.x + threadIdx.x;
    if (i < N) {
        int r = rowstart[i] + boff[i >> 10];
        rowstart[i] = r;
        invs[i] = rsqrtf((float)(1 + cnt[i]));
    }
    if (i == 0 && blockIdx.x == 0) rowstart[N] = E;
}

__global__ void k_fill_r(const int* __restrict__ ei, int E, const int* __restrict__ rowstart,
                         const unsigned* __restrict__ rank, unsigned* __restrict__ recs,
                         const int* __restrict__ flagp) {
    int is64 = *flagp;
    int e = blockIdx.x * blockDim.x + threadIdx.x;
    if (e < E) {
        int d = ld_dst(ei, e, E, is64);
        int s = ld_src(ei, e, E, is64);
        recs[rowstart[d] + rank[e]] = (unsigned)s;
    }
}

__global__ void k_agg_f32(const float* __restrict__ x, const int* __restrict__ rowstart,
                          const float* __restrict__ invs, const unsigned* __restrict__ recs,
                          int N, float* __restrict__ aggOut) {
    int node = blockIdx.x * 4 + (threadIdx.x >> 6);
    int lane = threadIdx.x & 63;
    if (node >= N) return;
    const float2* xr = (const float2*)x;
    float wn = invs[node];
    float2 xself = xr[(size_t)node * 64 + lane];
    float accx = wn * xself.x, accy = wn * xself.y;
    int e = rowstart[node], e1 = rowstart[node + 1];
    for (; e < e1; ++e) {
        unsigned s = recs[e];
        float w = invs[s];
        float2 v = xr[(size_t)s * 64 + lane];
        accx = fmaf(w, v.x, accx); accy = fmaf(w, v.y, accy);
    }
    float2 o; o.x = accx * wn; o.y = accy * wn;
    ((float2*)aggOut)[(size_t)node * 64 + lane] = o;
}

#define GROWS 32
__global__ __launch_bounds__(128) void k_gemm_f32(float* __restrict__ out, const float* __restrict__ Wm,
                                                  const float* __restrict__ bb,
                                                  const float* __restrict__ x, int N) {
    __shared__ float Ws[64 * DD];
    __shared__ float As[DD * GROWS];
    int t = threadIdx.x;
    int rowBase = blockIdx.x * GROWS;
    {
        int r = t & 31, kq = t >> 5;
        if (rowBase + r < N) {
            const float4* Av = (const float4*)(out + (size_t)(rowBase + r) * DD);
            #pragma unroll
            for (int q = 0; q < 8; q++) {
                float4 v = Av[kq * 8 + q];
                int k = (kq * 8 + q) * 4;
                As[(k + 0) * GROWS + r] = v.x;
                As[(k + 1) * GROWS + r] = v.y;
                As[(k + 2) * GROWS + r] = v.z;
                As[(k + 3) * GROWS + r] = v.w;
            }
        } else {
            #pragma unroll
            for (int q = 0; q < 8; q++) {
                int k = (kq * 8 + q) * 4;
                As[(k + 0) * GROWS + r] = 0.f;
                As[(k + 1) * GROWS + r] = 0.f;
                As[(k + 2) * GROWS + r] = 0.f;
                As[(k + 3) * GROWS + r] = 0.f;
            }
        }
    }
    int tx = t & 15, ty = t >> 4;
    int c0 = tx * 8, r0 = ty * 4;
    float acc[4][8];
    #pragma unroll
    for (int i = 0; i < 4; i++)
        #pragma unroll
        for (int j = 0; j < 8; j++) acc[i][j] = 0.f;
    for (int kk = 0; kk < DD; kk += 64) {
        __syncthreads();
        const float4* Wv = (const float4*)(Wm + (size_t)kk * DD);
        #pragma unroll
        for (int i = 0; i < 16; i++) ((float4*)Ws)[t + i * 128] = Wv[t + i * 128];
        __syncthreads();
        #pragma unroll 4
        for (int k = 0; k < 64; k++) {
            const float4 a = *(const float4*)&As[(kk + k) * GROWS + r0];
            const float4 w0 = *(const float4*)&Ws[k * DD + c0];
            const float4 w1 = *(const float4*)&Ws[k * DD + c0 + 4];
            const float av[4] = {a.x, a.y, a.z, a.w};
            const float wv[8] = {w0.x, w0.y, w0.z, w0.w, w1.x, w1.y, w1.z, w1.w};
            #pragma unroll
            for (int i = 0; i < 4; i++)
                #pragma unroll
                for (int j = 0; j < 8; j++) acc[i][j] = fmaf(av[i], wv[j], acc[i][j]);
        }
    }
    float bv[8];
    {
        float4 b0 = *(const float4*)&bb[c0];
        float4 b1 = *(const float4*)&bb[c0 + 4];
        bv[0] = b0.x; bv[1] = b0.y; bv[2] = b0.z; bv[3] = b0.w;
        bv[4] = b1.x; bv[5] = b1.y; bv[6] = b1.z; bv[7] = b1.w;
    }
    #pragma unroll
    for (int i = 0; i < 4; i++) {
        int row = rowBase + r0 + i;
        if (row < N) {
            const float4 xv0 = *(const float4*)&x[(size_t)row * DD + c0];
            const float4 xv1 = *(const float4*)&x[(size_t)row * DD + c0 + 4];
            float4 o0, o1;
            o0.x = fmaxf(acc[i][0] + bv[0], 0.f) + xv0.x;
            o0.y = fmaxf(acc[i][1] + bv[1], 0.f) + xv0.y;
            o0.z = fmaxf(acc[i][2] + bv[2], 0.f) + xv0.z;
            o0.w = fmaxf(acc[i][3] + bv[3], 0.f) + xv0.w;
            o1.x = fmaxf(acc[i][4] + bv[4], 0.f) + xv1.x;
            o1.y = fmaxf(acc[i][5] + bv[5], 0.f) + xv1.y;
            o1.z = fmaxf(acc[i][6] + bv[6], 0.f) + xv1.z;
            o1.w = fmaxf(acc[i][7] + bv[7], 0.f) + xv1.w;
            *(float4*)&out[(size_t)row * DD + c0] = o0;
            *(float4*)&out[(size_t)row * DD + c0 + 4] = o1;
        }
    }
}

extern "C" void kernel_launch(void* const* d_in, const int* in_sizes, int n_in,
                              void* d_out, int out_size, void* d_ws, size_t ws_size,
                              hipStream_t stream) {
    const float* x = (const float*)d_in[0];
    const float* W = (const float*)d_in[1];
    const float* b = (const float*)d_in[2];
    const int*   ei = (const int*)d_in[3];
    int N = in_sizes[0] / DD;
    int E = in_sizes[3] / 2;
    float* out = (float*)d_out;
    float* outTail = out + (size_t)N * DD;

    int NB = (N + 511) >> BSH;          // buckets of 512 nodes
    int nA = (E + EPB - 1) / EPB;       // A-pass blocks

    // new-path workspace layout (hs sized for bf16 fallback = superset of fp8)
    char* wsb = (char*)d_ws;
    size_t off = 0;
    unsigned* brec = (unsigned*)(wsb + off);  off += (size_t)E * 4;
    unsigned* recs = (unsigned*)(wsb + off);  off += (size_t)E * 4;
    unsigned* hs   = (unsigned*)(wsb + off);  off += (size_t)N * 64 * 4;
    ushort*   Wt   = (ushort*)(wsb + off);    off += (size_t)DD * DD * 2;
    int* H         = (int*)(wsb + off);       off += (size_t)nA * NB * 4;
    int* colsum    = (int*)(wsb + off);       off += (size_t)NB * 4;
    int* rowstart  = (int*)(wsb + off);       off += (size_t)(N + 1) * 4;
    float* invs    = (float*)(wsb + off);     off += (size_t)N * 4;

    bool newpath = (ws_size >= off) && (NB <= 256) && (nA <= 1024) && (N <= 131072) && (E >= 64);

    if (newpath) {
        kA1<<<nA + 64, 256, 0, stream>>>(ei, E, NB, nA, outTail, H, W, Wt);
        k_scanH1<<<NB, 256, 0, stream>>>(H, nA, NB, colsum);
        kA2<<<nA, 256, 0, stream>>>(ei, E, NB, H, colsum, brec);
        kB<<<NB, 512, 0, stream>>>(brec, colsum, NB, N, E, recs, rowstart, invs);
        k_gemm_h<<<(N + 63) / 64, 256, 0, stream>>>(x, Wt, invs, hs, N);
        k_agg_out<<<(N + 7) / 8, 256, 0, stream>>>(hs, rowstart, invs, recs, b, x, out, N);
    } else {
        // fallback: rank-based build + f32 compute (known good)
        off = 0;
        unsigned* recsF = (unsigned*)(wsb + off);  off += (size_t)E * 4;
        unsigned* rank  = (unsigned*)(wsb + off);  off += (size_t)E * 4;
        int* cnt        = (int*)(wsb + off);       off += (size_t)N * 4;
        int* rowstartF  = (int*)(wsb + off);       off += (size_t)(N + 1) * 4;
        float* invsF    = (float*)(wsb + off);     off += (size_t)N * 4;
        int* bsum       = (int*)(wsb + off);       off += 512 * 4;
        int* boff       = (int*)(wsb + off);       off += 512 * 4;
        int* flagF      = (int*)(wsb + off);

        hipMemsetAsync(cnt, 0, sizeof(int) * (size_t)N, stream);
        k_sniff<<<1, 1024, 0, stream>>>(ei, 1024, flagF);
        k_count_echo<<<(E + 255) / 256, 256, 0, stream>>>(ei, E, cnt, outTail, rank, flagF);
        int nblk = (N + 1023) / 1024;
        k_scan1<<<nblk, 1024, 0, stream>>>(cnt, N, rowstartF, bsum);
        k_scan2<<<1, 128, 0, stream>>>(bsum, nblk, boff);
        k_scan3<<<(N + 255) / 256, 256, 0, stream>>>(N, E, rowstartF, boff, cnt, invsF);
        k_fill_r<<<(E + 255) / 256, 256, 0, stream>>>(ei, E, rowstartF, rank, recsF, flagF);
        k_agg_f32<<<(N + 3) / 4, 256, 0, stream>>>(x, rowstartF, invsF, recsF, N, out);
        k_gemm_f32<<<(N + GROWS - 1) / GROWS, 128, 0, stream>>>(out, W, b, x, N);
    }
}